// Round 8
// baseline (260.567 us; speedup 1.0000x reference)
//
#include <hip/hip_runtime.h>
#include <hip/hip_bf16.h>
#include <stdint.h>

#define CB_SHIFT 11          // 2048 dst-nodes per coarse bucket
#define CB_NODES 2048
#define CAP 28672            // max edges per coarse bucket (mean ~24.5K, +26 sigma)
#define PT 4096              // edges per partition tile

static __device__ inline uint16_t f2bf(float f) {
    union { float f; uint32_t u; } v; v.f = f;
    uint32_t r = v.u + 0x7FFFu + ((v.u >> 16) & 1u);   // RNE
    return (uint16_t)(r >> 16);
}
static __device__ inline float bflo(uint32_t u) {      // low ushort as bf16
    union { uint32_t u; float f; } v; v.u = u << 16; return v.f;
}
static __device__ inline float bfhi(uint32_t u) {      // high ushort as bf16
    union { uint32_t u; float f; } v; v.u = u & 0xFFFF0000u; return v.f;
}
static __device__ inline float tanh_fast(float x) {    // 1 - 2/(1+e^2x), ~1e-6 rel
    x = fminf(fmaxf(x, -20.f), 20.f);
    float e = __expf(2.f * x);
    return fmaf(-2.f, __builtin_amdgcn_rcpf(e + 1.f), 1.f);
}

// ---- init: zero cursors/dhist + detect edge dtype (int64 pairs vs int32) ----
__global__ __launch_bounds__(256) void k_init(const uint32_t* __restrict__ e, int E,
                                              int* __restrict__ flag, int* __restrict__ gcur,
                                              int* __restrict__ dhist) {
    int t = threadIdx.x;
    dhist[t] = 0;
    if (t < 64) {
        gcur[t] = 0;
        int cnt = E < 1024 ? E : 1024;
        int nz = 0;
        for (int i = t; i < cnt; i += 64) nz |= (e[2 * i + 1] != 0u);
        int any = __any(nz);
        if (t == 0) *flag = any ? 0 : 1;  // 1 => int64
    }
}

// ---- coarse partition: edges -> 49 buckets of packed (src<<11 | dst&2047) ----
__global__ __launch_bounds__(256) void k_part(const uint32_t* __restrict__ e, int E,
                                              const int* __restrict__ flag,
                                              int* __restrict__ gcur,
                                              uint32_t* __restrict__ parts) {
    __shared__ int sh_hist[64], sh_off[64], sh_base[64];
    __shared__ uint32_t sh_buf[PT];
    __shared__ uint16_t sh_bkt[PT];
    int t = threadIdx.x;
    int tile0 = blockIdx.x * PT;
    int is64 = *flag;
    if (t < 64) sh_hist[t] = 0;
    __syncthreads();

    uint32_t rec[16]; int cb[16], rank[16];
    const uint2* e2p = (const uint2*)e;
    for (int j = 0; j < 16; ++j) {
        int idx = tile0 + j * 256 + t;
        cb[j] = -1;
        if (idx < E) {
            uint32_t s, d;
            if (is64) { s = e2p[idx].x; d = e2p[E + idx].x; }
            else      { s = e[idx];     d = e[E + idx]; }
            rec[j] = (s << CB_SHIFT) | (d & (CB_NODES - 1));
            cb[j] = (int)(d >> CB_SHIFT);
            rank[j] = atomicAdd(&sh_hist[cb[j]], 1);   // rank within (tile,bucket)
        }
    }
    __syncthreads();
    if (t < 64) {
        int cnt = sh_hist[t];
        int incl = cnt;
        for (int o = 1; o < 64; o <<= 1) {
            int v = __shfl_up(incl, o);
            if (t >= o) incl += v;
        }
        sh_off[t] = incl - cnt;
        sh_base[t] = (cnt > 0) ? atomicAdd(&gcur[t], cnt) : 0;
    }
    __syncthreads();
    for (int j = 0; j < 16; ++j) {
        if (cb[j] >= 0) {
            int slot = sh_off[cb[j]] + rank[j];
            sh_buf[slot] = rec[j];
            sh_bkt[slot] = (uint16_t)cb[j];
        }
    }
    __syncthreads();
    int total = min(PT, E - tile0);
    for (int i = t; i < total; i += 256) {
        int b = sh_bkt[i];
        int dest = sh_base[b] + (i - sh_off[b]);
        parts[(size_t)b * CAP + dest] = sh_buf[i];
    }
}

// ---- per bucket: hist -> scan -> dinv/rowbeg/rowend -> sorted col[] + degree-class hist ----
__global__ __launch_bounds__(1024) void k_build(const uint32_t* __restrict__ parts,
                                                const int* __restrict__ gcur,
                                                float* __restrict__ dinv,
                                                int* __restrict__ rowbeg,
                                                int* __restrict__ rowend,
                                                uint32_t* __restrict__ col,
                                                int* __restrict__ dhist, int N) {
    __shared__ int hist[CB_NODES], cur[CB_NODES], wsum[16], dh[256];
    int t = threadIdx.x, cb = blockIdx.x;
    int lane = t & 63, w = t >> 6;
    for (int i = t; i < CB_NODES; i += 1024) hist[i] = 0;
    if (t < 256) dh[t] = 0;
    __syncthreads();
    int cnt = gcur[cb];
    const uint32_t* rp = parts + (size_t)cb * CAP;
    for (int i = t; i < cnt; i += 1024) atomicAdd(&hist[rp[i] & (CB_NODES - 1)], 1);
    __syncthreads();
    int h0 = hist[2 * t], h1 = hist[2 * t + 1];
    int n0 = cb * CB_NODES;
    if (n0 + 2 * t < N)     atomicAdd(&dh[min(h0, 255)], 1);
    if (n0 + 2 * t + 1 < N) atomicAdd(&dh[min(h1, 255)], 1);
    int s = h0 + h1;
    int incl = s;
    for (int o = 1; o < 64; o <<= 1) {
        int v = __shfl_up(incl, o);
        if (lane >= o) incl += v;
    }
    if (lane == 63) wsum[w] = incl;
    __syncthreads();
    if (t < 16) {
        int v = wsum[t];
        int inc2 = v;
        for (int o = 1; o < 16; o <<= 1) {
            int u = __shfl_up(inc2, o);
            if (t >= o) inc2 += u;
        }
        wsum[t] = inc2 - v;   // exclusive
    }
    __syncthreads();
    int ex = wsum[w] + incl - s;
    int b0 = ex, b1 = ex + h0;
    cur[2 * t] = b0;
    cur[2 * t + 1] = b1;
    int base = cb * CAP;
    if (n0 + 2 * t < N) {
        rowbeg[n0 + 2 * t] = base + b0;
        rowend[n0 + 2 * t] = base + b0 + h0;
        dinv[n0 + 2 * t] = rsqrtf((float)(h0 + 1));
    }
    if (n0 + 2 * t + 1 < N) {
        rowbeg[n0 + 2 * t + 1] = base + b1;
        rowend[n0 + 2 * t + 1] = base + b1 + h1;
        dinv[n0 + 2 * t + 1] = rsqrtf((float)(h1 + 1));
    }
    __syncthreads();
    if (t < 256 && dh[t]) atomicAdd(&dhist[t], dh[t]);   // dh complete (sync above)
    for (int i = t; i < cnt; i += 1024) {
        uint32_t rec = rp[i];
        int pos = atomicAdd(&cur[rec & (CB_NODES - 1)], 1);
        col[base + pos] = rec >> CB_SHIFT;
    }
}

// ---- exclusive scan of 256 degree-class counts -> dcur ----
__global__ __launch_bounds__(256) void k_dscan(const int* __restrict__ dhist,
                                               int* __restrict__ dcur) {
    __shared__ int sd[256];
    int t = threadIdx.x;
    int v = dhist[t];
    sd[t] = v; __syncthreads();
    for (int o = 1; o < 256; o <<= 1) {
        int x = (t >= o) ? sd[t - o] : 0;
        __syncthreads();
        sd[t] += x;
        __syncthreads();
    }
    dcur[t] = sd[t] - v;   // exclusive
}

// ---- scatter nodes into degree-sorted perm4 = {rowbeg, deg, node, dinv} ----
__global__ __launch_bounds__(1024) void k_dperm(const int* __restrict__ rowbeg,
                                                const int* __restrict__ rowend,
                                                const float* __restrict__ dinv,
                                                int* __restrict__ dcur,
                                                int4* __restrict__ perm4, int N) {
    __shared__ int lh[256], lbase[256];
    int t = threadIdx.x;
    if (t < 256) lh[t] = 0;
    __syncthreads();
    int n = blockIdx.x * 1024 + t;
    int c = 0, rank = 0, beg = 0, deg = 0;
    if (n < N) {
        beg = rowbeg[n];
        deg = rowend[n] - beg;
        c = min(deg, 255);
        rank = atomicAdd(&lh[c], 1);
    }
    __syncthreads();
    if (t < 256 && lh[t]) lbase[t] = atomicAdd(&dcur[t], lh[t]);
    __syncthreads();
    if (n < N) {
        int pos = lbase[c] + rank;
        perm4[pos] = make_int4(beg, deg, n, __float_as_int(dinv[n]));
    }
}

// ---- h' = bf16( dinv[n] * (A@W)[n] )   (64x64 tile, 4x4 micro-tile) ----
__global__ __launch_bounds__(256) void k_gemm(const float* __restrict__ A,
                                              const float* __restrict__ W,
                                              const float* __restrict__ dinv,
                                              uint16_t* __restrict__ out, int N) {
    __shared__ __align__(16) float xT[64 * 68];
    __shared__ __align__(16) float Wl[64 * 64];
    int t = threadIdx.x;
#pragma unroll
    for (int j = 0; j < 16; ++j) Wl[j * 256 + t] = W[j * 256 + t];
    int n0 = blockIdx.x * 64;
    int nvalid = min(64, N - n0);
#pragma unroll
    for (int j = 0; j < 4; ++j) {
        int flat = j * 256 + t;
        int node = flat >> 4;
        int k4 = (flat & 15) * 4;
        float4 v = make_float4(0.f, 0.f, 0.f, 0.f);
        if (node < nvalid) v = *(const float4*)&A[(size_t)(n0 + node) * 64 + k4];
        xT[(k4 + 0) * 68 + node] = v.x;
        xT[(k4 + 1) * 68 + node] = v.y;
        xT[(k4 + 2) * 68 + node] = v.z;
        xT[(k4 + 3) * 68 + node] = v.w;
    }
    __syncthreads();
    int ng = t >> 4, cg = t & 15;
    float acc[4][4] = {};
#pragma unroll 8
    for (int k = 0; k < 64; ++k) {
        float4 a = *(const float4*)&xT[k * 68 + 4 * ng];
        float4 b = *(const float4*)&Wl[k * 64 + 4 * cg];
        float av[4] = {a.x, a.y, a.z, a.w};
        float bv[4] = {b.x, b.y, b.z, b.w};
#pragma unroll
        for (int i = 0; i < 4; ++i)
#pragma unroll
            for (int j = 0; j < 4; ++j) acc[i][j] = fmaf(av[i], bv[j], acc[i][j]);
    }
#pragma unroll
    for (int i = 0; i < 4; ++i) {
        int ln = 4 * ng + i;
        if (ln < nvalid) {
            int n = n0 + ln;
            float dv = dinv[n];
            ushort4 o;
            o.x = f2bf(acc[i][0] * dv);
            o.y = f2bf(acc[i][1] * dv);
            o.z = f2bf(acc[i][2] * dv);
            o.w = f2bf(acc[i][3] * dv);
            *(ushort4*)&out[(size_t)n * 64 + 4 * cg] = o;
        }
    }
}

// ---- agg over degree-sorted nodes: wave = 8 nodes x 8 feature-groups ----
// perm4[idx] = {rowbeg, deg, node, dinv}; sorted order makes wave-max deg
// ~= per-lane deg (no padding waste), loads packed into one int4.
__global__ __launch_bounds__(512) void k_agg(const uint16_t* __restrict__ h,
                                             const int4* __restrict__ perm4,
                                             const uint32_t* __restrict__ col,
                                             const float* __restrict__ bias,
                                             float* __restrict__ out, int N) {
    int t = threadIdx.x;
    int lane = t & 63, wid = t >> 6;
    int slot = lane >> 3;      // node slot 0..7
    int g = lane & 7;          // feature group: feats g*8 .. g*8+7
    const uint4* hp = (const uint4*)h;  // 8 x uint4 per node row
    float bv[8];
#pragma unroll
    for (int j = 0; j < 8; ++j) bv[j] = bias[g * 8 + j];
    int idx = (blockIdx.x * 8 + wid) * 8 + slot;
    bool valid = idx < N;
    int4 pi = make_int4(0, 0, 0, 0);
    if (valid) pi = perm4[idx];
    int rs = pi.x, deg = valid ? pi.y : 0, n = pi.z;
    float di = __int_as_float(pi.w);
    // wave-uniform max degree (sorted: ~= deg)
    int m = deg;
#pragma unroll
    for (int o = 1; o < 64; o <<= 1) m = max(m, __shfl_xor(m, o));
    float acc[8] = {};
#pragma unroll 4
    for (int it = 0; it < m; ++it) {
        if (it < deg) {
            int src = (int)col[rs + it];
            uint4 v = hp[(size_t)src * 8 + g];
            acc[0] += bflo(v.x); acc[1] += bfhi(v.x);
            acc[2] += bflo(v.y); acc[3] += bfhi(v.y);
            acc[4] += bflo(v.z); acc[5] += bfhi(v.z);
            acc[6] += bflo(v.w); acc[7] += bfhi(v.w);
        }
    }
    if (valid) {
        uint4 v = hp[(size_t)n * 8 + g];
        float hn[8] = {bflo(v.x), bfhi(v.x), bflo(v.y), bfhi(v.y),
                       bflo(v.z), bfhi(v.z), bflo(v.w), bfhi(v.w)};
        __align__(16) float o[8];
#pragma unroll
        for (int j = 0; j < 8; ++j)
            o[j] = tanh_fast(di * (acc[j] + hn[j]) + bv[j]);
        *(float4*)&out[(size_t)n * 64 + g * 8]     = *(float4*)&o[0];
        *(float4*)&out[(size_t)n * 64 + g * 8 + 4] = *(float4*)&o[4];
    }
}

// ---- classifier: out = h @ Wc + bc  (64 -> 32) ----
__global__ __launch_bounds__(256) void k_cls(const float* __restrict__ A,
                                             const float* __restrict__ W,
                                             const float* __restrict__ bc,
                                             float* __restrict__ out, int N) {
    __shared__ __align__(16) float xT[64 * 68];
    __shared__ __align__(16) float Wl[64 * 32];
    int t = threadIdx.x;
#pragma unroll
    for (int j = 0; j < 8; ++j) Wl[j * 256 + t] = W[j * 256 + t];
    int n0 = blockIdx.x * 64;
    int nvalid = min(64, N - n0);
#pragma unroll
    for (int j = 0; j < 4; ++j) {
        int flat = j * 256 + t;
        int node = flat >> 4;
        int k4 = (flat & 15) * 4;
        float4 v = make_float4(0.f, 0.f, 0.f, 0.f);
        if (node < nvalid) v = *(const float4*)&A[(size_t)(n0 + node) * 64 + k4];
        xT[(k4 + 0) * 68 + node] = v.x;
        xT[(k4 + 1) * 68 + node] = v.y;
        xT[(k4 + 2) * 68 + node] = v.z;
        xT[(k4 + 3) * 68 + node] = v.w;
    }
    __syncthreads();
    int ng = t >> 4, cg = t & 15;  // 4 nodes x 2 cols per thread
    float acc[4][2] = {};
#pragma unroll 8
    for (int k = 0; k < 64; ++k) {
        float4 a = *(const float4*)&xT[k * 68 + 4 * ng];
        float2 b = *(const float2*)&Wl[k * 32 + 2 * cg];
        float av[4] = {a.x, a.y, a.z, a.w};
#pragma unroll
        for (int i = 0; i < 4; ++i) {
            acc[i][0] = fmaf(av[i], b.x, acc[i][0]);
            acc[i][1] = fmaf(av[i], b.y, acc[i][1]);
        }
    }
    float2 bcv = *(const float2*)&bc[2 * cg];
#pragma unroll
    for (int i = 0; i < 4; ++i) {
        int ln = 4 * ng + i;
        if (ln < nvalid) {
            int n = n0 + ln;
            float2 o = make_float2(acc[i][0] + bcv.x, acc[i][1] + bcv.y);
            *(float2*)&out[(size_t)n * 32 + 2 * cg] = o;
        }
    }
}

extern "C" void kernel_launch(void* const* d_in, const int* in_sizes, int n_in,
                              void* d_out, int out_size, void* d_ws, size_t ws_size,
                              hipStream_t stream) {
    const float*    x     = (const float*)d_in[0];
    const uint32_t* edges = (const uint32_t*)d_in[1];
    const float*    W1    = (const float*)d_in[2];
    const float*    b1    = (const float*)d_in[3];
    const float*    W2    = (const float*)d_in[4];
    const float*    b2    = (const float*)d_in[5];
    const float*    Wc    = (const float*)d_in[6];
    const float*    bc    = (const float*)d_in[7];

    const int N   = in_sizes[0] / 64;
    const int E   = in_sizes[1] / 2;
    const int NBC = (N + CB_NODES - 1) >> CB_SHIFT;          // 49
    const int NTG = (N + 63) / 64;                           // 1563
    const int NTP = (E + PT - 1) / PT;                       // 293
    const int NAG = (N + 63) / 64;                           // 8 waves x 8 nodes per block
    const int NDP = (N + 1023) / 1024;                       // 98

    char* w = (char*)d_ws;
    size_t off = 0;
    auto alloc = [&](size_t bytes) {
        void* p = w + off;
        off = (off + bytes + 255) & ~(size_t)255;
        return p;
    };
    int*      flag   = (int*)alloc(4);
    int*      gcur   = (int*)alloc(64 * 4);
    int*      dhist  = (int*)alloc(256 * 4);
    int*      dcur   = (int*)alloc(256 * 4);
    float*    dinv   = (float*)alloc((size_t)N * 4);
    uint32_t* parts  = (uint32_t*)alloc((size_t)NBC * CAP * 4);
    uint32_t* col    = (uint32_t*)alloc((size_t)NBC * CAP * 4);
    int*      rowbeg = (int*)alloc((size_t)N * 4);
    int*      rowend = (int*)alloc((size_t)N * 4);
    int4*     perm4  = (int4*)alloc((size_t)N * 16);
    uint16_t* bufA   = (uint16_t*)alloc((size_t)N * 64 * 2);

    float* outc = (float*)d_out;            // chunk0: N x 32
    float* hfin = outc + (size_t)N * 32;    // chunk1: N x 64 (also h2 temp)

    hipLaunchKernelGGL(k_init, dim3(1), dim3(256), 0, stream, edges, E, flag, gcur, dhist);
    hipLaunchKernelGGL(k_part, dim3(NTP), dim3(256), 0, stream, edges, E, flag, gcur, parts);
    hipLaunchKernelGGL(k_build, dim3(NBC), dim3(1024), 0, stream, parts, gcur, dinv, rowbeg, rowend, col, dhist, N);
    hipLaunchKernelGGL(k_dscan, dim3(1), dim3(256), 0, stream, dhist, dcur);
    hipLaunchKernelGGL(k_dperm, dim3(NDP), dim3(1024), 0, stream, rowbeg, rowend, dinv, dcur, perm4, N);

    // layer 1: h1' = bf16(dinv*(x@W1)) -> bufA ; h2 = tanh(agg(h1')+b1) -> hfin
    hipLaunchKernelGGL(k_gemm, dim3(NTG), dim3(256), 0, stream, x, W1, dinv, bufA, N);
    hipLaunchKernelGGL(k_agg, dim3(NAG), dim3(512), 0, stream, bufA, perm4, col, b1, hfin, N);
    // layer 2: g' = bf16(dinv*(h2@W2)) -> bufA ; h = tanh(agg(g')+b2) -> hfin
    hipLaunchKernelGGL(k_gemm, dim3(NTG), dim3(256), 0, stream, hfin, W2, dinv, bufA, N);
    hipLaunchKernelGGL(k_agg, dim3(NAG), dim3(512), 0, stream, bufA, perm4, col, b2, hfin, N);
    // classifier
    hipLaunchKernelGGL(k_cls, dim3(NTG), dim3(256), 0, stream, hfin, Wc, bc, outc, N);
}

// Round 9
// 255.524 us; speedup vs baseline: 1.0197x; 1.0197x over previous
//
#include <hip/hip_runtime.h>
#include <hip/hip_bf16.h>
#include <stdint.h>

#define CB_SHIFT 11          // 2048 dst-nodes per coarse bucket
#define CB_NODES 2048
#define CAP 28672            // max edges per coarse bucket (mean ~24.5K, +26 sigma)
#define PT 4096              // edges per partition tile

static __device__ inline uint16_t f2bf(float f) {
    union { float f; uint32_t u; } v; v.f = f;
    uint32_t r = v.u + 0x7FFFu + ((v.u >> 16) & 1u);   // RNE
    return (uint16_t)(r >> 16);
}
static __device__ inline float bflo(uint32_t u) {      // low ushort as bf16
    union { uint32_t u; float f; } v; v.u = u << 16; return v.f;
}
static __device__ inline float bfhi(uint32_t u) {      // high ushort as bf16
    union { uint32_t u; float f; } v; v.u = u & 0xFFFF0000u; return v.f;
}
static __device__ inline float tanh_fast(float x) {    // 1 - 2/(1+e^2x), ~1e-6 rel
    x = fminf(fmaxf(x, -20.f), 20.f);
    float e = __expf(2.f * x);
    return fmaf(-2.f, __builtin_amdgcn_rcpf(e + 1.f), 1.f);
}

// ---- init: zero cursors/dhist + detect edge dtype (int64 pairs vs int32) ----
__global__ __launch_bounds__(256) void k_init(const uint32_t* __restrict__ e, int E,
                                              int* __restrict__ flag, int* __restrict__ gcur,
                                              int* __restrict__ dhist) {
    int t = threadIdx.x;
    dhist[t] = 0;
    if (t < 64) {
        gcur[t] = 0;
        int cnt = E < 1024 ? E : 1024;
        int nz = 0;
        for (int i = t; i < cnt; i += 64) nz |= (e[2 * i + 1] != 0u);
        int any = __any(nz);
        if (t == 0) *flag = any ? 0 : 1;  // 1 => int64
    }
}

// ---- coarse partition: edges -> 49 buckets of packed (src<<11 | dst&2047) ----
__global__ __launch_bounds__(256) void k_part(const uint32_t* __restrict__ e, int E,
                                              const int* __restrict__ flag,
                                              int* __restrict__ gcur,
                                              uint32_t* __restrict__ parts) {
    __shared__ int sh_hist[64], sh_off[64], sh_base[64];
    __shared__ uint32_t sh_buf[PT];
    __shared__ uint16_t sh_bkt[PT];
    int t = threadIdx.x;
    int tile0 = blockIdx.x * PT;
    int is64 = *flag;
    if (t < 64) sh_hist[t] = 0;
    __syncthreads();

    uint32_t rec[16]; int cb[16], rank[16];
    const uint2* e2p = (const uint2*)e;
    for (int j = 0; j < 16; ++j) {
        int idx = tile0 + j * 256 + t;
        cb[j] = -1;
        if (idx < E) {
            uint32_t s, d;
            if (is64) { s = e2p[idx].x; d = e2p[E + idx].x; }
            else      { s = e[idx];     d = e[E + idx]; }
            rec[j] = (s << CB_SHIFT) | (d & (CB_NODES - 1));
            cb[j] = (int)(d >> CB_SHIFT);
            rank[j] = atomicAdd(&sh_hist[cb[j]], 1);   // rank within (tile,bucket)
        }
    }
    __syncthreads();
    if (t < 64) {
        int cnt = sh_hist[t];
        int incl = cnt;
        for (int o = 1; o < 64; o <<= 1) {
            int v = __shfl_up(incl, o);
            if (t >= o) incl += v;
        }
        sh_off[t] = incl - cnt;
        sh_base[t] = (cnt > 0) ? atomicAdd(&gcur[t], cnt) : 0;
    }
    __syncthreads();
    for (int j = 0; j < 16; ++j) {
        if (cb[j] >= 0) {
            int slot = sh_off[cb[j]] + rank[j];
            sh_buf[slot] = rec[j];
            sh_bkt[slot] = (uint16_t)cb[j];
        }
    }
    __syncthreads();
    int total = min(PT, E - tile0);
    for (int i = t; i < total; i += 256) {
        int b = sh_bkt[i];
        int dest = sh_base[b] + (i - sh_off[b]);
        parts[(size_t)b * CAP + dest] = sh_buf[i];
    }
}

// ---- per bucket: hist -> scan -> dinv/rowbeg/rowend -> sorted col[] + degree-class hist ----
__global__ __launch_bounds__(1024) void k_build(const uint32_t* __restrict__ parts,
                                                const int* __restrict__ gcur,
                                                float* __restrict__ dinv,
                                                int* __restrict__ rowbeg,
                                                int* __restrict__ rowend,
                                                uint32_t* __restrict__ col,
                                                int* __restrict__ dhist, int N) {
    __shared__ int hist[CB_NODES], cur[CB_NODES], wsum[16], dh[256];
    int t = threadIdx.x, cb = blockIdx.x;
    int lane = t & 63, w = t >> 6;
    for (int i = t; i < CB_NODES; i += 1024) hist[i] = 0;
    if (t < 256) dh[t] = 0;
    __syncthreads();
    int cnt = gcur[cb];
    const uint32_t* rp = parts + (size_t)cb * CAP;
    for (int i = t; i < cnt; i += 1024) atomicAdd(&hist[rp[i] & (CB_NODES - 1)], 1);
    __syncthreads();
    int h0 = hist[2 * t], h1 = hist[2 * t + 1];
    int n0 = cb * CB_NODES;
    if (n0 + 2 * t < N)     atomicAdd(&dh[min(h0, 255)], 1);
    if (n0 + 2 * t + 1 < N) atomicAdd(&dh[min(h1, 255)], 1);
    int s = h0 + h1;
    int incl = s;
    for (int o = 1; o < 64; o <<= 1) {
        int v = __shfl_up(incl, o);
        if (lane >= o) incl += v;
    }
    if (lane == 63) wsum[w] = incl;
    __syncthreads();
    if (t < 16) {
        int v = wsum[t];
        int inc2 = v;
        for (int o = 1; o < 16; o <<= 1) {
            int u = __shfl_up(inc2, o);
            if (t >= o) inc2 += u;
        }
        wsum[t] = inc2 - v;   // exclusive
    }
    __syncthreads();
    int ex = wsum[w] + incl - s;
    int b0 = ex, b1 = ex + h0;
    cur[2 * t] = b0;
    cur[2 * t + 1] = b1;
    int base = cb * CAP;
    if (n0 + 2 * t < N) {
        rowbeg[n0 + 2 * t] = base + b0;
        rowend[n0 + 2 * t] = base + b0 + h0;
        dinv[n0 + 2 * t] = rsqrtf((float)(h0 + 1));
    }
    if (n0 + 2 * t + 1 < N) {
        rowbeg[n0 + 2 * t + 1] = base + b1;
        rowend[n0 + 2 * t + 1] = base + b1 + h1;
        dinv[n0 + 2 * t + 1] = rsqrtf((float)(h1 + 1));
    }
    __syncthreads();
    if (t < 256 && dh[t]) atomicAdd(&dhist[t], dh[t]);   // dh complete (sync above)
    for (int i = t; i < cnt; i += 1024) {
        uint32_t rec = rp[i];
        int pos = atomicAdd(&cur[rec & (CB_NODES - 1)], 1);
        col[base + pos] = rec >> CB_SHIFT;
    }
}

// ---- exclusive scan of 256 degree-class counts -> dcur ----
__global__ __launch_bounds__(256) void k_dscan(const int* __restrict__ dhist,
                                               int* __restrict__ dcur) {
    __shared__ int sd[256];
    int t = threadIdx.x;
    int v = dhist[t];
    sd[t] = v; __syncthreads();
    for (int o = 1; o < 256; o <<= 1) {
        int x = (t >= o) ? sd[t - o] : 0;
        __syncthreads();
        sd[t] += x;
        __syncthreads();
    }
    dcur[t] = sd[t] - v;   // exclusive
}

// ---- scatter nodes into DESCENDING-degree perm4 = {rowbeg, deg, node, dinv} ----
// Descending order: longest rows dispatch first -> no straggler tail.
__global__ __launch_bounds__(1024) void k_dperm(const int* __restrict__ rowbeg,
                                                const int* __restrict__ rowend,
                                                const float* __restrict__ dinv,
                                                int* __restrict__ dcur,
                                                int4* __restrict__ perm4, int N) {
    __shared__ int lh[256], lbase[256];
    int t = threadIdx.x;
    if (t < 256) lh[t] = 0;
    __syncthreads();
    int n = blockIdx.x * 1024 + t;
    int c = 0, rank = 0, beg = 0, deg = 0;
    if (n < N) {
        beg = rowbeg[n];
        deg = rowend[n] - beg;
        c = min(deg, 255);
        rank = atomicAdd(&lh[c], 1);
    }
    __syncthreads();
    if (t < 256 && lh[t]) lbase[t] = atomicAdd(&dcur[t], lh[t]);
    __syncthreads();
    if (n < N) {
        int pos = lbase[c] + rank;
        perm4[(N - 1) - pos] = make_int4(beg, deg, n, __float_as_int(dinv[n]));
    }
}

// ---- h' = bf16( dinv[n] * (A@W)[n] )   (64x64 tile, 4x4 micro-tile) ----
__global__ __launch_bounds__(256) void k_gemm(const float* __restrict__ A,
                                              const float* __restrict__ W,
                                              const float* __restrict__ dinv,
                                              uint16_t* __restrict__ out, int N) {
    __shared__ __align__(16) float xT[64 * 68];
    __shared__ __align__(16) float Wl[64 * 64];
    int t = threadIdx.x;
#pragma unroll
    for (int j = 0; j < 16; ++j) Wl[j * 256 + t] = W[j * 256 + t];
    int n0 = blockIdx.x * 64;
    int nvalid = min(64, N - n0);
#pragma unroll
    for (int j = 0; j < 4; ++j) {
        int flat = j * 256 + t;
        int node = flat >> 4;
        int k4 = (flat & 15) * 4;
        float4 v = make_float4(0.f, 0.f, 0.f, 0.f);
        if (node < nvalid) v = *(const float4*)&A[(size_t)(n0 + node) * 64 + k4];
        xT[(k4 + 0) * 68 + node] = v.x;
        xT[(k4 + 1) * 68 + node] = v.y;
        xT[(k4 + 2) * 68 + node] = v.z;
        xT[(k4 + 3) * 68 + node] = v.w;
    }
    __syncthreads();
    int ng = t >> 4, cg = t & 15;
    float acc[4][4] = {};
#pragma unroll 8
    for (int k = 0; k < 64; ++k) {
        float4 a = *(const float4*)&xT[k * 68 + 4 * ng];
        float4 b = *(const float4*)&Wl[k * 64 + 4 * cg];
        float av[4] = {a.x, a.y, a.z, a.w};
        float bv[4] = {b.x, b.y, b.z, b.w};
#pragma unroll
        for (int i = 0; i < 4; ++i)
#pragma unroll
            for (int j = 0; j < 4; ++j) acc[i][j] = fmaf(av[i], bv[j], acc[i][j]);
    }
#pragma unroll
    for (int i = 0; i < 4; ++i) {
        int ln = 4 * ng + i;
        if (ln < nvalid) {
            int n = n0 + ln;
            float dv = dinv[n];
            ushort4 o;
            o.x = f2bf(acc[i][0] * dv);
            o.y = f2bf(acc[i][1] * dv);
            o.z = f2bf(acc[i][2] * dv);
            o.w = f2bf(acc[i][3] * dv);
            *(ushort4*)&out[(size_t)n * 64 + 4 * cg] = o;
        }
    }
}

// ---- agg: wave = 4 nodes x 2 edge-slots x 8 feature-groups ----
// Two lanes split each node's edge list (even/odd) -> half the serial
// latency depth; one xor-8 shuffle per acc merges. Epilogue split: each
// lane does 4 tanh + one 16B store (256B contiguous per node).
__global__ __launch_bounds__(512) void k_agg(const uint16_t* __restrict__ h,
                                             const int4* __restrict__ perm4,
                                             const uint32_t* __restrict__ col,
                                             const float* __restrict__ bias,
                                             float* __restrict__ out, int N) {
    int t = threadIdx.x;
    int lane = t & 63, wid = t >> 6;
    int slot = lane >> 4;        // node slot 0..3
    int sub  = (lane >> 3) & 1;  // edge-parity 0/1 (bit 3)
    int g = lane & 7;            // feature group: feats g*8 .. g*8+7
    const uint4* hp = (const uint4*)h;  // 8 x uint4 per node row
    float bv[4];
#pragma unroll
    for (int j = 0; j < 4; ++j) bv[j] = bias[g * 8 + sub * 4 + j];
    int idx = (blockIdx.x * 8 + wid) * 4 + slot;
    bool valid = idx < N;
    int4 pi = make_int4(0, 0, 0, 0);
    if (valid) pi = perm4[idx];
    int rs = pi.x, deg = valid ? pi.y : 0, n = pi.z;
    float di = __int_as_float(pi.w);
    // wave-uniform max degree (sorted: ~= deg)
    int m = deg;
#pragma unroll
    for (int o = 1; o < 64; o <<= 1) m = max(m, __shfl_xor(m, o));
    int trips = (m + 1) >> 1;
    float acc[8] = {};
#pragma unroll 4
    for (int it = 0; it < trips; ++it) {
        int e = 2 * it + sub;
        if (e < deg) {
            int src = (int)col[rs + e];
            uint4 v = hp[(size_t)src * 8 + g];
            acc[0] += bflo(v.x); acc[1] += bfhi(v.x);
            acc[2] += bflo(v.y); acc[3] += bfhi(v.y);
            acc[4] += bflo(v.z); acc[5] += bfhi(v.z);
            acc[6] += bflo(v.w); acc[7] += bfhi(v.w);
        }
    }
#pragma unroll
    for (int j = 0; j < 8; ++j) acc[j] += __shfl_xor(acc[j], 8);
    if (valid) {
        // static selects (no runtime-indexed register array -> no scratch)
        float s0 = sub ? acc[4] : acc[0];
        float s1 = sub ? acc[5] : acc[1];
        float s2 = sub ? acc[6] : acc[2];
        float s3 = sub ? acc[7] : acc[3];
        uint2 v = *(const uint2*)&h[(size_t)n * 64 + g * 8 + sub * 4];
        float hn0 = bflo(v.x), hn1 = bfhi(v.x), hn2 = bflo(v.y), hn3 = bfhi(v.y);
        __align__(16) float o[4];
        o[0] = tanh_fast(di * (s0 + hn0) + bv[0]);
        o[1] = tanh_fast(di * (s1 + hn1) + bv[1]);
        o[2] = tanh_fast(di * (s2 + hn2) + bv[2]);
        o[3] = tanh_fast(di * (s3 + hn3) + bv[3]);
        *(float4*)&out[(size_t)n * 64 + g * 8 + sub * 4] = *(float4*)&o[0];
    }
}

// ---- classifier: out = h @ Wc + bc  (64 -> 32) ----
__global__ __launch_bounds__(256) void k_cls(const float* __restrict__ A,
                                             const float* __restrict__ W,
                                             const float* __restrict__ bc,
                                             float* __restrict__ out, int N) {
    __shared__ __align__(16) float xT[64 * 68];
    __shared__ __align__(16) float Wl[64 * 32];
    int t = threadIdx.x;
#pragma unroll
    for (int j = 0; j < 8; ++j) Wl[j * 256 + t] = W[j * 256 + t];
    int n0 = blockIdx.x * 64;
    int nvalid = min(64, N - n0);
#pragma unroll
    for (int j = 0; j < 4; ++j) {
        int flat = j * 256 + t;
        int node = flat >> 4;
        int k4 = (flat & 15) * 4;
        float4 v = make_float4(0.f, 0.f, 0.f, 0.f);
        if (node < nvalid) v = *(const float4*)&A[(size_t)(n0 + node) * 64 + k4];
        xT[(k4 + 0) * 68 + node] = v.x;
        xT[(k4 + 1) * 68 + node] = v.y;
        xT[(k4 + 2) * 68 + node] = v.z;
        xT[(k4 + 3) * 68 + node] = v.w;
    }
    __syncthreads();
    int ng = t >> 4, cg = t & 15;  // 4 nodes x 2 cols per thread
    float acc[4][2] = {};
#pragma unroll 8
    for (int k = 0; k < 64; ++k) {
        float4 a = *(const float4*)&xT[k * 68 + 4 * ng];
        float2 b = *(const float2*)&Wl[k * 32 + 2 * cg];
        float av[4] = {a.x, a.y, a.z, a.w};
#pragma unroll
        for (int i = 0; i < 4; ++i) {
            acc[i][0] = fmaf(av[i], b.x, acc[i][0]);
            acc[i][1] = fmaf(av[i], b.y, acc[i][1]);
        }
    }
    float2 bcv = *(const float2*)&bc[2 * cg];
#pragma unroll
    for (int i = 0; i < 4; ++i) {
        int ln = 4 * ng + i;
        if (ln < nvalid) {
            int n = n0 + ln;
            float2 o = make_float2(acc[i][0] + bcv.x, acc[i][1] + bcv.y);
            *(float2*)&out[(size_t)n * 32 + 2 * cg] = o;
        }
    }
}

extern "C" void kernel_launch(void* const* d_in, const int* in_sizes, int n_in,
                              void* d_out, int out_size, void* d_ws, size_t ws_size,
                              hipStream_t stream) {
    const float*    x     = (const float*)d_in[0];
    const uint32_t* edges = (const uint32_t*)d_in[1];
    const float*    W1    = (const float*)d_in[2];
    const float*    b1    = (const float*)d_in[3];
    const float*    W2    = (const float*)d_in[4];
    const float*    b2    = (const float*)d_in[5];
    const float*    Wc    = (const float*)d_in[6];
    const float*    bc    = (const float*)d_in[7];

    const int N   = in_sizes[0] / 64;
    const int E   = in_sizes[1] / 2;
    const int NBC = (N + CB_NODES - 1) >> CB_SHIFT;          // 49
    const int NTG = (N + 63) / 64;                           // 1563
    const int NTP = (E + PT - 1) / PT;                       // 293
    const int NAG = (N + 31) / 32;                           // 8 waves x 4 nodes per block
    const int NDP = (N + 1023) / 1024;                       // 98

    char* w = (char*)d_ws;
    size_t off = 0;
    auto alloc = [&](size_t bytes) {
        void* p = w + off;
        off = (off + bytes + 255) & ~(size_t)255;
        return p;
    };
    int*      flag   = (int*)alloc(4);
    int*      gcur   = (int*)alloc(64 * 4);
    int*      dhist  = (int*)alloc(256 * 4);
    int*      dcur   = (int*)alloc(256 * 4);
    float*    dinv   = (float*)alloc((size_t)N * 4);
    uint32_t* parts  = (uint32_t*)alloc((size_t)NBC * CAP * 4);
    uint32_t* col    = (uint32_t*)alloc((size_t)NBC * CAP * 4);
    int*      rowbeg = (int*)alloc((size_t)N * 4);
    int*      rowend = (int*)alloc((size_t)N * 4);
    int4*     perm4  = (int4*)alloc((size_t)N * 16);
    uint16_t* bufA   = (uint16_t*)alloc((size_t)N * 64 * 2);

    float* outc = (float*)d_out;            // chunk0: N x 32
    float* hfin = outc + (size_t)N * 32;    // chunk1: N x 64 (also h2 temp)

    hipLaunchKernelGGL(k_init, dim3(1), dim3(256), 0, stream, edges, E, flag, gcur, dhist);
    hipLaunchKernelGGL(k_part, dim3(NTP), dim3(256), 0, stream, edges, E, flag, gcur, parts);
    hipLaunchKernelGGL(k_build, dim3(NBC), dim3(1024), 0, stream, parts, gcur, dinv, rowbeg, rowend, col, dhist, N);
    hipLaunchKernelGGL(k_dscan, dim3(1), dim3(256), 0, stream, dhist, dcur);
    hipLaunchKernelGGL(k_dperm, dim3(NDP), dim3(1024), 0, stream, rowbeg, rowend, dinv, dcur, perm4, N);

    // layer 1: h1' = bf16(dinv*(x@W1)) -> bufA ; h2 = tanh(agg(h1')+b1) -> hfin
    hipLaunchKernelGGL(k_gemm, dim3(NTG), dim3(256), 0, stream, x, W1, dinv, bufA, N);
    hipLaunchKernelGGL(k_agg, dim3(NAG), dim3(512), 0, stream, bufA, perm4, col, b1, hfin, N);
    // layer 2: g' = bf16(dinv*(h2@W2)) -> bufA ; h = tanh(agg(g')+b2) -> hfin
    hipLaunchKernelGGL(k_gemm, dim3(NTG), dim3(256), 0, stream, hfin, W2, dinv, bufA, N);
    hipLaunchKernelGGL(k_agg, dim3(NAG), dim3(512), 0, stream, bufA, perm4, col, b2, hfin, N);
    // classifier
    hipLaunchKernelGGL(k_cls, dim3(NTG), dim3(256), 0, stream, hfin, Wc, bc, outc, N);
}

// Round 10
// 243.715 us; speedup vs baseline: 1.0691x; 1.0485x over previous
//
#include <hip/hip_runtime.h>
#include <hip/hip_bf16.h>
#include <stdint.h>

#define CB_SHIFT 8           // 256 dst-nodes per bucket
#define CB_NODES 256
#define CAP 3584             // max edges per bucket (mean ~3072, +9 sigma)
#define NBINS 512            // bucket bins in k_part (391 used)
#define PT 4096              // edges per partition tile

static __device__ inline uint16_t f2bf(float f) {
    union { float f; uint32_t u; } v; v.f = f;
    uint32_t r = v.u + 0x7FFFu + ((v.u >> 16) & 1u);   // RNE
    return (uint16_t)(r >> 16);
}
static __device__ inline float bflo(uint32_t u) {      // low ushort as bf16
    union { uint32_t u; float f; } v; v.u = u << 16; return v.f;
}
static __device__ inline float bfhi(uint32_t u) {      // high ushort as bf16
    union { uint32_t u; float f; } v; v.u = u & 0xFFFF0000u; return v.f;
}
static __device__ inline float bfu(uint16_t u) {
    union { uint32_t u; float f; } v; v.u = ((uint32_t)u) << 16; return v.f;
}
static __device__ inline float tanh_fast(float x) {    // 1 - 2/(1+e^2x), ~1e-6 rel
    x = fminf(fmaxf(x, -20.f), 20.f);
    float e = __expf(2.f * x);
    return fmaf(-2.f, __builtin_amdgcn_rcpf(e + 1.f), 1.f);
}

// ---- init: zero cursors/dhist + detect edge dtype (int64 pairs vs int32) ----
__global__ __launch_bounds__(256) void k_init(const uint32_t* __restrict__ e, int E,
                                              int* __restrict__ flag, int* __restrict__ gcur,
                                              int* __restrict__ dhist) {
    int t = threadIdx.x;
    dhist[t] = 0;
    gcur[t] = 0;
    gcur[256 + t] = 0;
    if (t < 64) {
        int cnt = E < 1024 ? E : 1024;
        int nz = 0;
        for (int i = t; i < cnt; i += 64) nz |= (e[2 * i + 1] != 0u);
        int any = __any(nz);
        if (t == 0) *flag = any ? 0 : 1;  // 1 => int64
    }
}

// ---- coarse partition: edges -> 391 buckets of packed (src<<8 | dst&255) ----
__global__ __launch_bounds__(256) void k_part(const uint32_t* __restrict__ e, int E,
                                              const int* __restrict__ flag,
                                              int* __restrict__ gcur,
                                              uint32_t* __restrict__ parts) {
    __shared__ int sh_hist[NBINS], sh_off[NBINS], sh_base[NBINS], pw[4];
    __shared__ uint32_t sh_buf[PT];
    __shared__ uint16_t sh_bkt[PT];
    int t = threadIdx.x;
    int tile0 = blockIdx.x * PT;
    int is64 = *flag;
    sh_hist[t] = 0;
    sh_hist[256 + t] = 0;
    __syncthreads();

    uint32_t rec[16]; int cb[16], rank[16];
    const uint2* e2p = (const uint2*)e;
    for (int j = 0; j < 16; ++j) {
        int idx = tile0 + j * 256 + t;
        cb[j] = -1;
        if (idx < E) {
            uint32_t s, d;
            if (is64) { s = e2p[idx].x; d = e2p[E + idx].x; }
            else      { s = e[idx];     d = e[E + idx]; }
            rec[j] = (s << CB_SHIFT) | (d & (CB_NODES - 1));
            cb[j] = (int)(d >> CB_SHIFT);
            rank[j] = atomicAdd(&sh_hist[cb[j]], 1);   // rank within (tile,bucket)
        }
    }
    __syncthreads();
    int c0 = sh_hist[2 * t], c1 = sh_hist[2 * t + 1];
    int s2 = c0 + c1;
    int incl = s2;
    {
        int lane = t & 63;
        for (int o = 1; o < 64; o <<= 1) {
            int v = __shfl_up(incl, o);
            if (lane >= o) incl += v;
        }
        if (lane == 63) pw[t >> 6] = incl;
    }
    __syncthreads();
    if (t == 0) {
        int r = 0;
        for (int k = 0; k < 4; ++k) { int v = pw[k]; pw[k] = r; r += v; }
    }
    __syncthreads();
    {
        int ex = pw[t >> 6] + incl - s2;
        sh_off[2 * t] = ex;
        sh_off[2 * t + 1] = ex + c0;
        sh_base[2 * t]     = c0 ? atomicAdd(&gcur[2 * t], c0) : 0;
        sh_base[2 * t + 1] = c1 ? atomicAdd(&gcur[2 * t + 1], c1) : 0;
    }
    __syncthreads();
    for (int j = 0; j < 16; ++j) {
        if (cb[j] >= 0) {
            int slot = sh_off[cb[j]] + rank[j];
            sh_buf[slot] = rec[j];
            sh_bkt[slot] = (uint16_t)cb[j];
        }
    }
    __syncthreads();
    int total = min(PT, E - tile0);
    for (int i = t; i < total; i += 256) {
        int b = sh_bkt[i];
        int dest = sh_base[b] + (i - sh_off[b]);
        parts[(size_t)b * CAP + dest] = sh_buf[i];
    }
}

// ---- per bucket: hist -> scan -> rows/dinv -> LDS counting-sort -> coalesced col ----
__global__ __launch_bounds__(512) void k_build(const uint32_t* __restrict__ parts,
                                               const int* __restrict__ gcur,
                                               float* __restrict__ dinv,
                                               int* __restrict__ rowbeg,
                                               int* __restrict__ rowend,
                                               uint32_t* __restrict__ col,
                                               int* __restrict__ dhist, int N) {
    __shared__ int hist[CB_NODES], cur[CB_NODES], dh[256], wsum4[4];
    __shared__ uint32_t sbuf[CAP];
    int t = threadIdx.x, cb = blockIdx.x;
    if (t < 256) { hist[t] = 0; dh[t] = 0; }
    __syncthreads();
    int cnt = gcur[cb];
    const uint32_t* rp = parts + (size_t)cb * CAP;
    for (int i = t; i < cnt; i += 512) atomicAdd(&hist[rp[i] & (CB_NODES - 1)], 1);
    __syncthreads();
    int h = 0, incl = 0;
    if (t < 256) {
        h = hist[t];
        int lane = t & 63;
        incl = h;
        for (int o = 1; o < 64; o <<= 1) {
            int v = __shfl_up(incl, o);
            if (lane >= o) incl += v;
        }
        if (lane == 63) wsum4[t >> 6] = incl;
    }
    __syncthreads();
    if (t == 0) {
        int r = 0;
        for (int k = 0; k < 4; ++k) { int v = wsum4[k]; wsum4[k] = r; r += v; }
    }
    __syncthreads();
    if (t < 256) {
        int ex = wsum4[t >> 6] + incl - h;
        cur[t] = ex;
        int n = cb * CB_NODES + t;
        int base = cb * CAP;
        if (n < N) {
            rowbeg[n] = base + ex;
            rowend[n] = base + ex + h;
            dinv[n] = rsqrtf((float)(h + 1));
            atomicAdd(&dh[min(h, 255)], 1);
        }
    }
    __syncthreads();
    if (t < 256 && dh[t]) atomicAdd(&dhist[t], dh[t]);
    for (int i = t; i < cnt; i += 512) {
        uint32_t rec = rp[i];
        int pos = atomicAdd(&cur[rec & (CB_NODES - 1)], 1);
        sbuf[pos] = rec >> CB_SHIFT;
    }
    __syncthreads();
    int base = cb * CAP;
    for (int i = t; i < cnt; i += 512) col[base + i] = sbuf[i];   // coalesced
}

// ---- exclusive scan of 256 degree-class counts -> dcur ----
__global__ __launch_bounds__(256) void k_dscan(const int* __restrict__ dhist,
                                               int* __restrict__ dcur) {
    __shared__ int sd[256];
    int t = threadIdx.x;
    int v = dhist[t];
    sd[t] = v; __syncthreads();
    for (int o = 1; o < 256; o <<= 1) {
        int x = (t >= o) ? sd[t - o] : 0;
        __syncthreads();
        sd[t] += x;
        __syncthreads();
    }
    dcur[t] = sd[t] - v;   // exclusive
}

// ---- scatter nodes into DESCENDING-degree perm4 = {rowbeg, deg, node, dinv} ----
__global__ __launch_bounds__(1024) void k_dperm(const int* __restrict__ rowbeg,
                                                const int* __restrict__ rowend,
                                                const float* __restrict__ dinv,
                                                int* __restrict__ dcur,
                                                int4* __restrict__ perm4, int N) {
    __shared__ int lh[256], lbase[256];
    int t = threadIdx.x;
    if (t < 256) lh[t] = 0;
    __syncthreads();
    int n = blockIdx.x * 1024 + t;
    int c = 0, rank = 0, beg = 0, deg = 0;
    if (n < N) {
        beg = rowbeg[n];
        deg = rowend[n] - beg;
        c = min(deg, 255);
        rank = atomicAdd(&lh[c], 1);
    }
    __syncthreads();
    if (t < 256 && lh[t]) lbase[t] = atomicAdd(&dcur[t], lh[t]);
    __syncthreads();
    if (n < N) {
        int pos = lbase[c] + rank;
        perm4[(N - 1) - pos] = make_int4(beg, deg, n, __float_as_int(dinv[n]));
    }
}

// ---- h' = bf16( dinv[n] * (A@W)[n] ), A f32 or bf16 ----
template<int ABF16>
__global__ __launch_bounds__(256) void k_gemm(const void* __restrict__ Ap,
                                              const float* __restrict__ W,
                                              const float* __restrict__ dinv,
                                              uint16_t* __restrict__ out, int N) {
    __shared__ __align__(16) float xT[64 * 68];
    __shared__ __align__(16) float Wl[64 * 64];
    int t = threadIdx.x;
#pragma unroll
    for (int j = 0; j < 16; ++j) Wl[j * 256 + t] = W[j * 256 + t];
    int n0 = blockIdx.x * 64;
    int nvalid = min(64, N - n0);
#pragma unroll
    for (int j = 0; j < 4; ++j) {
        int flat = j * 256 + t;
        int node = flat >> 4;
        int k4 = (flat & 15) * 4;
        float4 v = make_float4(0.f, 0.f, 0.f, 0.f);
        if (node < nvalid) {
            if (ABF16) {
                ushort4 u = *((const ushort4*)Ap + ((size_t)(n0 + node) * 16 + (k4 >> 2)));
                v = make_float4(bfu(u.x), bfu(u.y), bfu(u.z), bfu(u.w));
            } else {
                v = *(const float4*)((const float*)Ap + (size_t)(n0 + node) * 64 + k4);
            }
        }
        xT[(k4 + 0) * 68 + node] = v.x;
        xT[(k4 + 1) * 68 + node] = v.y;
        xT[(k4 + 2) * 68 + node] = v.z;
        xT[(k4 + 3) * 68 + node] = v.w;
    }
    __syncthreads();
    int ng = t >> 4, cg = t & 15;
    float acc[4][4] = {};
#pragma unroll 8
    for (int k = 0; k < 64; ++k) {
        float4 a = *(const float4*)&xT[k * 68 + 4 * ng];
        float4 b = *(const float4*)&Wl[k * 64 + 4 * cg];
        float av[4] = {a.x, a.y, a.z, a.w};
        float bv[4] = {b.x, b.y, b.z, b.w};
#pragma unroll
        for (int i = 0; i < 4; ++i)
#pragma unroll
            for (int j = 0; j < 4; ++j) acc[i][j] = fmaf(av[i], bv[j], acc[i][j]);
    }
#pragma unroll
    for (int i = 0; i < 4; ++i) {
        int ln = 4 * ng + i;
        if (ln < nvalid) {
            int n = n0 + ln;
            float dv = dinv[n];
            ushort4 o;
            o.x = f2bf(acc[i][0] * dv);
            o.y = f2bf(acc[i][1] * dv);
            o.z = f2bf(acc[i][2] * dv);
            o.w = f2bf(acc[i][3] * dv);
            *(ushort4*)&out[(size_t)n * 64 + 4 * cg] = o;
        }
    }
}

// ---- agg: wave = 4 nodes x 2 edge-slots x 8 feature-groups; out f32 or bf16 ----
template<int OBF16>
__global__ __launch_bounds__(512) void k_agg(const uint16_t* __restrict__ h,
                                             const int4* __restrict__ perm4,
                                             const uint32_t* __restrict__ col,
                                             const float* __restrict__ bias,
                                             void* __restrict__ out, int N) {
    int t = threadIdx.x;
    int lane = t & 63, wid = t >> 6;
    int sub  = (lane >> 3) & 1;  // edge-parity 0/1
    int g = lane & 7;            // feature group
    const uint4* hp = (const uint4*)h;  // 8 x uint4 per node row
    float bv[4];
#pragma unroll
    for (int j = 0; j < 4; ++j) bv[j] = bias[g * 8 + sub * 4 + j];
    int slot = lane >> 4;
    int idx = (blockIdx.x * 8 + wid) * 4 + slot;
    bool valid = idx < N;
    int4 pi = make_int4(0, 0, 0, 0);
    if (valid) pi = perm4[idx];
    int rs = pi.x, deg = valid ? pi.y : 0, n = pi.z;
    float di = __int_as_float(pi.w);
    int m = deg;
#pragma unroll
    for (int o = 1; o < 64; o <<= 1) m = max(m, __shfl_xor(m, o));
    int trips = (m + 1) >> 1;
    float acc[8] = {};
#pragma unroll 8
    for (int it = 0; it < trips; ++it) {
        int e = 2 * it + sub;
        if (e < deg) {
            int src = (int)col[rs + e];
            uint4 v = hp[(size_t)src * 8 + g];
            acc[0] += bflo(v.x); acc[1] += bfhi(v.x);
            acc[2] += bflo(v.y); acc[3] += bfhi(v.y);
            acc[4] += bflo(v.z); acc[5] += bfhi(v.z);
            acc[6] += bflo(v.w); acc[7] += bfhi(v.w);
        }
    }
#pragma unroll
    for (int j = 0; j < 8; ++j) acc[j] += __shfl_xor(acc[j], 8);
    if (valid) {
        float s0 = sub ? acc[4] : acc[0];
        float s1 = sub ? acc[5] : acc[1];
        float s2 = sub ? acc[6] : acc[2];
        float s3 = sub ? acc[7] : acc[3];
        uint2 v = *(const uint2*)&h[(size_t)n * 64 + g * 8 + sub * 4];
        float hn0 = bflo(v.x), hn1 = bfhi(v.x), hn2 = bflo(v.y), hn3 = bfhi(v.y);
        float r0 = tanh_fast(di * (s0 + hn0) + bv[0]);
        float r1 = tanh_fast(di * (s1 + hn1) + bv[1]);
        float r2 = tanh_fast(di * (s2 + hn2) + bv[2]);
        float r3 = tanh_fast(di * (s3 + hn3) + bv[3]);
        if (OBF16) {
            ushort4 ob;
            ob.x = f2bf(r0); ob.y = f2bf(r1); ob.z = f2bf(r2); ob.w = f2bf(r3);
            *(ushort4*)&((uint16_t*)out)[(size_t)n * 64 + g * 8 + sub * 4] = ob;
        } else {
            __align__(16) float o[4] = {r0, r1, r2, r3};
            *(float4*)&((float*)out)[(size_t)n * 64 + g * 8 + sub * 4] = *(float4*)&o[0];
        }
    }
}

// ---- classifier: out = h @ Wc + bc  (64 -> 32) ----
__global__ __launch_bounds__(256) void k_cls(const float* __restrict__ A,
                                             const float* __restrict__ W,
                                             const float* __restrict__ bc,
                                             float* __restrict__ out, int N) {
    __shared__ __align__(16) float xT[64 * 68];
    __shared__ __align__(16) float Wl[64 * 32];
    int t = threadIdx.x;
#pragma unroll
    for (int j = 0; j < 8; ++j) Wl[j * 256 + t] = W[j * 256 + t];
    int n0 = blockIdx.x * 64;
    int nvalid = min(64, N - n0);
#pragma unroll
    for (int j = 0; j < 4; ++j) {
        int flat = j * 256 + t;
        int node = flat >> 4;
        int k4 = (flat & 15) * 4;
        float4 v = make_float4(0.f, 0.f, 0.f, 0.f);
        if (node < nvalid) v = *(const float4*)&A[(size_t)(n0 + node) * 64 + k4];
        xT[(k4 + 0) * 68 + node] = v.x;
        xT[(k4 + 1) * 68 + node] = v.y;
        xT[(k4 + 2) * 68 + node] = v.z;
        xT[(k4 + 3) * 68 + node] = v.w;
    }
    __syncthreads();
    int ng = t >> 4, cg = t & 15;
    float acc[4][2] = {};
#pragma unroll 8
    for (int k = 0; k < 64; ++k) {
        float4 a = *(const float4*)&xT[k * 68 + 4 * ng];
        float2 b = *(const float2*)&Wl[k * 32 + 2 * cg];
        float av[4] = {a.x, a.y, a.z, a.w};
#pragma unroll
        for (int i = 0; i < 4; ++i) {
            acc[i][0] = fmaf(av[i], b.x, acc[i][0]);
            acc[i][1] = fmaf(av[i], b.y, acc[i][1]);
        }
    }
    float2 bcv = *(const float2*)&bc[2 * cg];
#pragma unroll
    for (int i = 0; i < 4; ++i) {
        int ln = 4 * ng + i;
        if (ln < nvalid) {
            int n = n0 + ln;
            float2 o = make_float2(acc[i][0] + bcv.x, acc[i][1] + bcv.y);
            *(float2*)&out[(size_t)n * 32 + 2 * cg] = o;
        }
    }
}

extern "C" void kernel_launch(void* const* d_in, const int* in_sizes, int n_in,
                              void* d_out, int out_size, void* d_ws, size_t ws_size,
                              hipStream_t stream) {
    const float*    x     = (const float*)d_in[0];
    const uint32_t* edges = (const uint32_t*)d_in[1];
    const float*    W1    = (const float*)d_in[2];
    const float*    b1    = (const float*)d_in[3];
    const float*    W2    = (const float*)d_in[4];
    const float*    b2    = (const float*)d_in[5];
    const float*    Wc    = (const float*)d_in[6];
    const float*    bc    = (const float*)d_in[7];

    const int N   = in_sizes[0] / 64;
    const int E   = in_sizes[1] / 2;
    const int NBC = (N + CB_NODES - 1) >> CB_SHIFT;          // 391
    const int NTG = (N + 63) / 64;                           // 1563
    const int NTP = (E + PT - 1) / PT;                       // 293
    const int NAG = (N + 31) / 32;                           // 8 waves x 4 nodes per block
    const int NDP = (N + 1023) / 1024;                       // 98

    char* w = (char*)d_ws;
    size_t off = 0;
    auto alloc = [&](size_t bytes) {
        void* p = w + off;
        off = (off + bytes + 255) & ~(size_t)255;
        return p;
    };
    int*      flag   = (int*)alloc(4);
    int*      gcur   = (int*)alloc(NBINS * 4);
    int*      dhist  = (int*)alloc(256 * 4);
    int*      dcur   = (int*)alloc(256 * 4);
    float*    dinv   = (float*)alloc((size_t)N * 4);
    uint32_t* parts  = (uint32_t*)alloc((size_t)NBC * CAP * 4);
    uint32_t* col    = (uint32_t*)alloc((size_t)NBC * CAP * 4);
    int*      rowbeg = (int*)alloc((size_t)N * 4);
    int*      rowend = (int*)alloc((size_t)N * 4);
    uint16_t* bufA   = (uint16_t*)alloc((size_t)N * 64 * 2);
    uint16_t* bufB   = (uint16_t*)alloc((size_t)N * 64 * 2);
    int4*     perm4  = (int4*)parts;   // parts dead after k_build; alias

    float* outc = (float*)d_out;            // chunk0: N x 32
    float* hfin = outc + (size_t)N * 32;    // chunk1: N x 64

    hipLaunchKernelGGL(k_init, dim3(1), dim3(256), 0, stream, edges, E, flag, gcur, dhist);
    hipLaunchKernelGGL(k_part, dim3(NTP), dim3(256), 0, stream, edges, E, flag, gcur, parts);
    hipLaunchKernelGGL(k_build, dim3(NBC), dim3(512), 0, stream, parts, gcur, dinv, rowbeg, rowend, col, dhist, N);
    hipLaunchKernelGGL(k_dscan, dim3(1), dim3(256), 0, stream, dhist, dcur);
    hipLaunchKernelGGL(k_dperm, dim3(NDP), dim3(1024), 0, stream, rowbeg, rowend, dinv, dcur, perm4, N);

    // layer 1: h1' = bf16(dinv*(x@W1)) -> bufA ; h2 = bf16(tanh(agg(h1')+b1)) -> bufB
    hipLaunchKernelGGL(HIP_KERNEL_NAME(k_gemm<0>), dim3(NTG), dim3(256), 0, stream,
                       (const void*)x, W1, dinv, bufA, N);
    hipLaunchKernelGGL(HIP_KERNEL_NAME(k_agg<1>), dim3(NAG), dim3(512), 0, stream,
                       bufA, perm4, col, b1, (void*)bufB, N);
    // layer 2: g' = bf16(dinv*(h2@W2)) -> bufA ; h = tanh(agg(g')+b2) -> hfin (f32)
    hipLaunchKernelGGL(HIP_KERNEL_NAME(k_gemm<1>), dim3(NTG), dim3(256), 0, stream,
                       (const void*)bufB, W2, dinv, bufA, N);
    hipLaunchKernelGGL(HIP_KERNEL_NAME(k_agg<0>), dim3(NAG), dim3(512), 0, stream,
                       bufA, perm4, col, b2, (void*)hfin, N);
    // classifier
    hipLaunchKernelGGL(k_cls, dim3(NTG), dim3(256), 0, stream, hfin, Wc, bc, outc, N);
}

// Round 11
// 236.210 us; speedup vs baseline: 1.1031x; 1.0318x over previous
//
#include <hip/hip_runtime.h>
#include <hip/hip_bf16.h>
#include <stdint.h>

#define CB_SHIFT 8           // 256 dst-nodes per bucket
#define CB_NODES 256
#define CAP 3584             // max edges per bucket (mean ~3072, +9 sigma)
#define NBINS 512            // bucket bins in k_part (391 used)
#define PT 4096              // edges per partition tile

static __device__ inline uint16_t f2bf(float f) {
    union { float f; uint32_t u; } v; v.f = f;
    uint32_t r = v.u + 0x7FFFu + ((v.u >> 16) & 1u);   // RNE
    return (uint16_t)(r >> 16);
}
static __device__ inline float bflo(uint32_t u) {      // low ushort as bf16
    union { uint32_t u; float f; } v; v.u = u << 16; return v.f;
}
static __device__ inline float bfhi(uint32_t u) {      // high ushort as bf16
    union { uint32_t u; float f; } v; v.u = u & 0xFFFF0000u; return v.f;
}
static __device__ inline float bfu(uint16_t u) {
    union { uint32_t u; float f; } v; v.u = ((uint32_t)u) << 16; return v.f;
}
static __device__ inline float tanh_fast(float x) {    // 1 - 2/(1+e^2x), ~1e-6 rel
    x = fminf(fmaxf(x, -20.f), 20.f);
    float e = __expf(2.f * x);
    return fmaf(-2.f, __builtin_amdgcn_rcpf(e + 1.f), 1.f);
}

// ---- init: zero cursors/dhist + detect edge dtype (int64 pairs vs int32) ----
__global__ __launch_bounds__(256) void k_init(const uint32_t* __restrict__ e, int E,
                                              int* __restrict__ flag, int* __restrict__ gcur,
                                              int* __restrict__ dhist) {
    int t = threadIdx.x;
    dhist[t] = 0;
    gcur[t] = 0;
    gcur[256 + t] = 0;
    if (t < 64) {
        int cnt = E < 1024 ? E : 1024;
        int nz = 0;
        for (int i = t; i < cnt; i += 64) nz |= (e[2 * i + 1] != 0u);
        int any = __any(nz);
        if (t == 0) *flag = any ? 0 : 1;  // 1 => int64
    }
}

// ---- coarse partition: edges -> 391 buckets of packed (src<<8 | dst&255) ----
// 512 threads, 8 edges/thread: half the serial rank-atomic depth of the
// previous 256x16 shape; one scan bin per thread.
__global__ __launch_bounds__(512) void k_part(const uint32_t* __restrict__ e, int E,
                                              const int* __restrict__ flag,
                                              int* __restrict__ gcur,
                                              uint32_t* __restrict__ parts) {
    __shared__ int sh_hist[NBINS], sh_off[NBINS], sh_base[NBINS], pw[8];
    __shared__ uint32_t sh_buf[PT];
    __shared__ uint16_t sh_bkt[PT];
    int t = threadIdx.x;
    int tile0 = blockIdx.x * PT;
    int is64 = *flag;
    sh_hist[t] = 0;
    __syncthreads();

    uint32_t rec[8]; int cb[8], rank[8];
    const uint2* e2p = (const uint2*)e;
#pragma unroll
    for (int j = 0; j < 8; ++j) {
        int idx = tile0 + j * 512 + t;
        cb[j] = -1;
        if (idx < E) {
            uint32_t s, d;
            if (is64) { s = e2p[idx].x; d = e2p[E + idx].x; }
            else      { s = e[idx];     d = e[E + idx]; }
            rec[j] = (s << CB_SHIFT) | (d & (CB_NODES - 1));
            cb[j] = (int)(d >> CB_SHIFT);
            rank[j] = atomicAdd(&sh_hist[cb[j]], 1);   // rank within (tile,bucket)
        }
    }
    __syncthreads();
    int c = sh_hist[t];
    int lane = t & 63, w = t >> 6;
    int incl = c;
    for (int o = 1; o < 64; o <<= 1) {
        int v = __shfl_up(incl, o);
        if (lane >= o) incl += v;
    }
    if (lane == 63) pw[w] = incl;
    __syncthreads();
    if (t < 8) {
        int v = pw[t];
        int inc2 = v;
#pragma unroll
        for (int o = 1; o < 8; o <<= 1) {
            int u = __shfl_up(inc2, o);
            if (t >= o) inc2 += u;
        }
        pw[t] = inc2 - v;   // exclusive
    }
    __syncthreads();
    {
        int ex = pw[w] + incl - c;
        sh_off[t] = ex;
        sh_base[t] = c ? atomicAdd(&gcur[t], c) : 0;
    }
    __syncthreads();
#pragma unroll
    for (int j = 0; j < 8; ++j) {
        if (cb[j] >= 0) {
            int slot = sh_off[cb[j]] + rank[j];
            sh_buf[slot] = rec[j];
            sh_bkt[slot] = (uint16_t)cb[j];
        }
    }
    __syncthreads();
    int total = min(PT, E - tile0);
    for (int i = t; i < total; i += 512) {
        int b = sh_bkt[i];
        int dest = sh_base[b] + (i - sh_off[b]);
        parts[(size_t)b * CAP + dest] = sh_buf[i];
    }
}

// ---- per bucket: hist -> scan -> rows/dinv -> LDS counting-sort -> coalesced col ----
__global__ __launch_bounds__(512) void k_build(const uint32_t* __restrict__ parts,
                                               const int* __restrict__ gcur,
                                               float* __restrict__ dinv,
                                               int* __restrict__ rowbeg,
                                               int* __restrict__ rowend,
                                               uint32_t* __restrict__ col,
                                               int* __restrict__ dhist, int N) {
    __shared__ int hist[CB_NODES], cur[CB_NODES], dh[256], wsum4[4];
    __shared__ uint32_t sbuf[CAP];
    int t = threadIdx.x, cb = blockIdx.x;
    if (t < 256) { hist[t] = 0; dh[t] = 0; }
    __syncthreads();
    int cnt = gcur[cb];
    const uint32_t* rp = parts + (size_t)cb * CAP;
    for (int i = t; i < cnt; i += 512) atomicAdd(&hist[rp[i] & (CB_NODES - 1)], 1);
    __syncthreads();
    int h = 0, incl = 0;
    if (t < 256) {
        h = hist[t];
        int lane = t & 63;
        incl = h;
        for (int o = 1; o < 64; o <<= 1) {
            int v = __shfl_up(incl, o);
            if (lane >= o) incl += v;
        }
        if (lane == 63) wsum4[t >> 6] = incl;
    }
    __syncthreads();
    if (t == 0) {
        int r = 0;
        for (int k = 0; k < 4; ++k) { int v = wsum4[k]; wsum4[k] = r; r += v; }
    }
    __syncthreads();
    if (t < 256) {
        int ex = wsum4[t >> 6] + incl - h;
        cur[t] = ex;
        int n = cb * CB_NODES + t;
        int base = cb * CAP;
        if (n < N) {
            rowbeg[n] = base + ex;
            rowend[n] = base + ex + h;
            dinv[n] = rsqrtf((float)(h + 1));
            atomicAdd(&dh[min(h, 255)], 1);
        }
    }
    __syncthreads();
    if (t < 256 && dh[t]) atomicAdd(&dhist[t], dh[t]);
    for (int i = t; i < cnt; i += 512) {
        uint32_t rec = rp[i];
        int pos = atomicAdd(&cur[rec & (CB_NODES - 1)], 1);
        sbuf[pos] = rec >> CB_SHIFT;
    }
    __syncthreads();
    int base = cb * CAP;
    for (int i = t; i < cnt; i += 512) col[base + i] = sbuf[i];   // coalesced
}

// ---- exclusive scan of 256 degree-class counts -> dcur ----
__global__ __launch_bounds__(256) void k_dscan(const int* __restrict__ dhist,
                                               int* __restrict__ dcur) {
    __shared__ int sd[256];
    int t = threadIdx.x;
    int v = dhist[t];
    sd[t] = v; __syncthreads();
    for (int o = 1; o < 256; o <<= 1) {
        int x = (t >= o) ? sd[t - o] : 0;
        __syncthreads();
        sd[t] += x;
        __syncthreads();
    }
    dcur[t] = sd[t] - v;   // exclusive
}

// ---- scatter nodes into DESCENDING-degree perm4 = {rowbeg, deg, node, dinv} ----
__global__ __launch_bounds__(1024) void k_dperm(const int* __restrict__ rowbeg,
                                                const int* __restrict__ rowend,
                                                const float* __restrict__ dinv,
                                                int* __restrict__ dcur,
                                                int4* __restrict__ perm4, int N) {
    __shared__ int lh[256], lbase[256];
    int t = threadIdx.x;
    if (t < 256) lh[t] = 0;
    __syncthreads();
    int n = blockIdx.x * 1024 + t;
    int c = 0, rank = 0, beg = 0, deg = 0;
    if (n < N) {
        beg = rowbeg[n];
        deg = rowend[n] - beg;
        c = min(deg, 255);
        rank = atomicAdd(&lh[c], 1);
    }
    __syncthreads();
    if (t < 256 && lh[t]) lbase[t] = atomicAdd(&dcur[t], lh[t]);
    __syncthreads();
    if (n < N) {
        int pos = lbase[c] + rank;
        perm4[(N - 1) - pos] = make_int4(beg, deg, n, __float_as_int(dinv[n]));
    }
}

// ---- h' = bf16( dinv[n] * (A@W)[n] ), A f32 or bf16 ----
template<int ABF16>
__global__ __launch_bounds__(256) void k_gemm(const void* __restrict__ Ap,
                                              const float* __restrict__ W,
                                              const float* __restrict__ dinv,
                                              uint16_t* __restrict__ out, int N) {
    __shared__ __align__(16) float xT[64 * 68];
    __shared__ __align__(16) float Wl[64 * 64];
    int t = threadIdx.x;
#pragma unroll
    for (int j = 0; j < 16; ++j) Wl[j * 256 + t] = W[j * 256 + t];
    int n0 = blockIdx.x * 64;
    int nvalid = min(64, N - n0);
#pragma unroll
    for (int j = 0; j < 4; ++j) {
        int flat = j * 256 + t;
        int node = flat >> 4;
        int k4 = (flat & 15) * 4;
        float4 v = make_float4(0.f, 0.f, 0.f, 0.f);
        if (node < nvalid) {
            if (ABF16) {
                ushort4 u = *((const ushort4*)Ap + ((size_t)(n0 + node) * 16 + (k4 >> 2)));
                v = make_float4(bfu(u.x), bfu(u.y), bfu(u.z), bfu(u.w));
            } else {
                v = *(const float4*)((const float*)Ap + (size_t)(n0 + node) * 64 + k4);
            }
        }
        xT[(k4 + 0) * 68 + node] = v.x;
        xT[(k4 + 1) * 68 + node] = v.y;
        xT[(k4 + 2) * 68 + node] = v.z;
        xT[(k4 + 3) * 68 + node] = v.w;
    }
    __syncthreads();
    int ng = t >> 4, cg = t & 15;
    float acc[4][4] = {};
#pragma unroll 8
    for (int k = 0; k < 64; ++k) {
        float4 a = *(const float4*)&xT[k * 68 + 4 * ng];
        float4 b = *(const float4*)&Wl[k * 64 + 4 * cg];
        float av[4] = {a.x, a.y, a.z, a.w};
        float bv[4] = {b.x, b.y, b.z, b.w};
#pragma unroll
        for (int i = 0; i < 4; ++i)
#pragma unroll
            for (int j = 0; j < 4; ++j) acc[i][j] = fmaf(av[i], bv[j], acc[i][j]);
    }
#pragma unroll
    for (int i = 0; i < 4; ++i) {
        int ln = 4 * ng + i;
        if (ln < nvalid) {
            int n = n0 + ln;
            float dv = dinv[n];
            ushort4 o;
            o.x = f2bf(acc[i][0] * dv);
            o.y = f2bf(acc[i][1] * dv);
            o.z = f2bf(acc[i][2] * dv);
            o.w = f2bf(acc[i][3] * dv);
            *(ushort4*)&out[(size_t)n * 64 + 4 * cg] = o;
        }
    }
}

// ---- agg: wave = 4 nodes x 2 edge-slots x 8 feature-groups ----
// OBF16: write bf16 (layer-1 intermediate). CLS: fuse classifier — after the
// epilogue the wave stages each node's 64-f32 h row in LDS (same-wave
// write->read, no barrier) and each lane computes 2 output columns.
template<int OBF16, int CLS>
__global__ __launch_bounds__(512) void k_agg(const uint16_t* __restrict__ h,
                                             const int4* __restrict__ perm4,
                                             const uint32_t* __restrict__ col,
                                             const float* __restrict__ bias,
                                             void* __restrict__ out,
                                             const float* __restrict__ Wc,
                                             const float* __restrict__ bc,
                                             float* __restrict__ outc, int N) {
    __shared__ __align__(16) float WcL[CLS ? 64 * 32 : 1];
    __shared__ __align__(16) float hstage[CLS ? 8 : 1][4][64];
    int t = threadIdx.x;
    if (CLS) {
#pragma unroll
        for (int j = 0; j < 4; ++j) WcL[j * 512 + t] = Wc[j * 512 + t];
        __syncthreads();
    }
    int lane = t & 63, wid = t >> 6;
    int sub  = (lane >> 3) & 1;  // edge-parity 0/1
    int g = lane & 7;            // feature group
    const uint4* hp = (const uint4*)h;  // 8 x uint4 per node row
    float bv[4];
#pragma unroll
    for (int j = 0; j < 4; ++j) bv[j] = bias[g * 8 + sub * 4 + j];
    int slot = lane >> 4;
    int idx = (blockIdx.x * 8 + wid) * 4 + slot;
    bool valid = idx < N;
    int4 pi = make_int4(0, 0, 0, 0);
    if (valid) pi = perm4[idx];
    int rs = pi.x, deg = valid ? pi.y : 0, n = pi.z;
    float di = __int_as_float(pi.w);
    int m = deg;
#pragma unroll
    for (int o = 1; o < 64; o <<= 1) m = max(m, __shfl_xor(m, o));
    int trips = (m + 1) >> 1;
    float acc[8] = {};
#pragma unroll 8
    for (int it = 0; it < trips; ++it) {
        int e = 2 * it + sub;
        if (e < deg) {
            int src = (int)col[rs + e];
            uint4 v = hp[(size_t)src * 8 + g];
            acc[0] += bflo(v.x); acc[1] += bfhi(v.x);
            acc[2] += bflo(v.y); acc[3] += bfhi(v.y);
            acc[4] += bflo(v.z); acc[5] += bfhi(v.z);
            acc[6] += bflo(v.w); acc[7] += bfhi(v.w);
        }
    }
#pragma unroll
    for (int j = 0; j < 8; ++j) acc[j] += __shfl_xor(acc[j], 8);
    if (valid) {
        float s0 = sub ? acc[4] : acc[0];
        float s1 = sub ? acc[5] : acc[1];
        float s2 = sub ? acc[6] : acc[2];
        float s3 = sub ? acc[7] : acc[3];
        uint2 v = *(const uint2*)&h[(size_t)n * 64 + g * 8 + sub * 4];
        float hn0 = bflo(v.x), hn1 = bfhi(v.x), hn2 = bflo(v.y), hn3 = bfhi(v.y);
        float r0 = tanh_fast(di * (s0 + hn0) + bv[0]);
        float r1 = tanh_fast(di * (s1 + hn1) + bv[1]);
        float r2 = tanh_fast(di * (s2 + hn2) + bv[2]);
        float r3 = tanh_fast(di * (s3 + hn3) + bv[3]);
        if (OBF16) {
            ushort4 ob;
            ob.x = f2bf(r0); ob.y = f2bf(r1); ob.z = f2bf(r2); ob.w = f2bf(r3);
            *(ushort4*)&((uint16_t*)out)[(size_t)n * 64 + g * 8 + sub * 4] = ob;
        } else {
            __align__(16) float o[4] = {r0, r1, r2, r3};
            *(float4*)&((float*)out)[(size_t)n * 64 + g * 8 + sub * 4] = *(float4*)&o[0];
        }
        if (CLS)
            *(float4*)&hstage[wid][slot][g * 8 + sub * 4] = make_float4(r0, r1, r2, r3);
    }
    if (CLS) {
        // same-wave LDS exchange: all 16 lanes of this slot wrote above.
        int q = lane & 15;                 // 2 cols per lane: 2q, 2q+1
        if (valid) {
            float a0 = 0.f, a1 = 0.f;
#pragma unroll
            for (int k = 0; k < 64; k += 4) {
                float4 hv = *(const float4*)&hstage[wid][slot][k];
                float2 w0 = *(const float2*)&WcL[(k + 0) * 32 + 2 * q];
                float2 w1 = *(const float2*)&WcL[(k + 1) * 32 + 2 * q];
                float2 w2 = *(const float2*)&WcL[(k + 2) * 32 + 2 * q];
                float2 w3 = *(const float2*)&WcL[(k + 3) * 32 + 2 * q];
                a0 = fmaf(hv.x, w0.x, a0); a1 = fmaf(hv.x, w0.y, a1);
                a0 = fmaf(hv.y, w1.x, a0); a1 = fmaf(hv.y, w1.y, a1);
                a0 = fmaf(hv.z, w2.x, a0); a1 = fmaf(hv.z, w2.y, a1);
                a0 = fmaf(hv.w, w3.x, a0); a1 = fmaf(hv.w, w3.y, a1);
            }
            float2 bcv = *(const float2*)&bc[2 * q];
            float2 o = make_float2(a0 + bcv.x, a1 + bcv.y);
            *(float2*)&outc[(size_t)n * 32 + 2 * q] = o;
        }
    }
}

extern "C" void kernel_launch(void* const* d_in, const int* in_sizes, int n_in,
                              void* d_out, int out_size, void* d_ws, size_t ws_size,
                              hipStream_t stream) {
    const float*    x     = (const float*)d_in[0];
    const uint32_t* edges = (const uint32_t*)d_in[1];
    const float*    W1    = (const float*)d_in[2];
    const float*    b1    = (const float*)d_in[3];
    const float*    W2    = (const float*)d_in[4];
    const float*    b2    = (const float*)d_in[5];
    const float*    Wc    = (const float*)d_in[6];
    const float*    bc    = (const float*)d_in[7];

    const int N   = in_sizes[0] / 64;
    const int E   = in_sizes[1] / 2;
    const int NBC = (N + CB_NODES - 1) >> CB_SHIFT;          // 391
    const int NTG = (N + 63) / 64;                           // 1563
    const int NTP = (E + PT - 1) / PT;                       // 293
    const int NAG = (N + 31) / 32;                           // 8 waves x 4 nodes per block
    const int NDP = (N + 1023) / 1024;                       // 98

    char* w = (char*)d_ws;
    size_t off = 0;
    auto alloc = [&](size_t bytes) {
        void* p = w + off;
        off = (off + bytes + 255) & ~(size_t)255;
        return p;
    };
    int*      flag   = (int*)alloc(4);
    int*      gcur   = (int*)alloc(NBINS * 4);
    int*      dhist  = (int*)alloc(256 * 4);
    int*      dcur   = (int*)alloc(256 * 4);
    float*    dinv   = (float*)alloc((size_t)N * 4);
    uint32_t* parts  = (uint32_t*)alloc((size_t)NBC * CAP * 4);
    uint32_t* col    = (uint32_t*)alloc((size_t)NBC * CAP * 4);
    int*      rowbeg = (int*)alloc((size_t)N * 4);
    int*      rowend = (int*)alloc((size_t)N * 4);
    uint16_t* bufA   = (uint16_t*)alloc((size_t)N * 64 * 2);
    uint16_t* bufB   = (uint16_t*)alloc((size_t)N * 64 * 2);
    int4*     perm4  = (int4*)parts;   // parts dead after k_build; alias

    float* outc = (float*)d_out;            // chunk0: N x 32
    float* hfin = outc + (size_t)N * 32;    // chunk1: N x 64

    hipLaunchKernelGGL(k_init, dim3(1), dim3(256), 0, stream, edges, E, flag, gcur, dhist);
    hipLaunchKernelGGL(k_part, dim3(NTP), dim3(512), 0, stream, edges, E, flag, gcur, parts);
    hipLaunchKernelGGL(k_build, dim3(NBC), dim3(512), 0, stream, parts, gcur, dinv, rowbeg, rowend, col, dhist, N);
    hipLaunchKernelGGL(k_dscan, dim3(1), dim3(256), 0, stream, dhist, dcur);
    hipLaunchKernelGGL(k_dperm, dim3(NDP), dim3(1024), 0, stream, rowbeg, rowend, dinv, dcur, perm4, N);

    // layer 1: h1' = bf16(dinv*(x@W1)) -> bufA ; h2 = bf16(tanh(agg(h1')+b1)) -> bufB
    hipLaunchKernelGGL(HIP_KERNEL_NAME(k_gemm<0>), dim3(NTG), dim3(256), 0, stream,
                       (const void*)x, W1, dinv, bufA, N);
    hipLaunchKernelGGL(HIP_KERNEL_NAME(k_agg<1, 0>), dim3(NAG), dim3(512), 0, stream,
                       bufA, perm4, col, b1, (void*)bufB, (const float*)nullptr,
                       (const float*)nullptr, (float*)nullptr, N);
    // layer 2: g' = bf16(dinv*(h2@W2)) -> bufA ; h = tanh(agg(g')+b2) -> hfin (f32)
    //          + fused classifier: outc = h @ Wc + bc
    hipLaunchKernelGGL(HIP_KERNEL_NAME(k_gemm<1>), dim3(NTG), dim3(256), 0, stream,
                       (const void*)bufB, W2, dinv, bufA, N);
    hipLaunchKernelGGL(HIP_KERNEL_NAME(k_agg<0, 1>), dim3(NAG), dim3(512), 0, stream,
                       bufA, perm4, col, b2, (void*)hfin, Wc, bc, outc, N);
}

// Round 12
// 233.517 us; speedup vs baseline: 1.1158x; 1.0115x over previous
//
#include <hip/hip_runtime.h>
#include <hip/hip_bf16.h>
#include <stdint.h>

#define CB_SHIFT 8           // 256 dst-nodes per bucket
#define CB_NODES 256
#define CAP 3584             // max edges per bucket (mean ~3072, +9 sigma)
#define NBINS 512            // bucket bins in k_part (391 used)
#define PT 4096              // edges per partition tile

static __device__ inline uint16_t f2bf(float f) {
    union { float f; uint32_t u; } v; v.f = f;
    uint32_t r = v.u + 0x7FFFu + ((v.u >> 16) & 1u);   // RNE
    return (uint16_t)(r >> 16);
}
static __device__ inline float bflo(uint32_t u) {      // low ushort as bf16
    union { uint32_t u; float f; } v; v.u = u << 16; return v.f;
}
static __device__ inline float bfhi(uint32_t u) {      // high ushort as bf16
    union { uint32_t u; float f; } v; v.u = u & 0xFFFF0000u; return v.f;
}
static __device__ inline float bfu(uint16_t u) {
    union { uint32_t u; float f; } v; v.u = ((uint32_t)u) << 16; return v.f;
}
static __device__ inline float tanh_fast(float x) {    // 1 - 2/(1+e^2x), ~1e-6 rel
    x = fminf(fmaxf(x, -20.f), 20.f);
    float e = __expf(2.f * x);
    return fmaf(-2.f, __builtin_amdgcn_rcpf(e + 1.f), 1.f);
}

// ---- init: zero cursors + detect edge dtype (int64 pairs vs int32) ----
__global__ __launch_bounds__(256) void k_init(const uint32_t* __restrict__ e, int E,
                                              int* __restrict__ flag, int* __restrict__ gcur) {
    int t = threadIdx.x;
    gcur[t] = 0;
    gcur[256 + t] = 0;
    if (t < 64) {
        int cnt = E < 1024 ? E : 1024;
        int nz = 0;
        for (int i = t; i < cnt; i += 64) nz |= (e[2 * i + 1] != 0u);
        int any = __any(nz);
        if (t == 0) *flag = any ? 0 : 1;  // 1 => int64
    }
}

// ---- coarse partition: edges -> 391 buckets of packed (src<<8 | dst&255) ----
__global__ __launch_bounds__(512) void k_part(const uint32_t* __restrict__ e, int E,
                                              const int* __restrict__ flag,
                                              int* __restrict__ gcur,
                                              uint32_t* __restrict__ parts) {
    __shared__ int sh_hist[NBINS], sh_off[NBINS], sh_base[NBINS], pw[8];
    __shared__ uint32_t sh_buf[PT];
    __shared__ uint16_t sh_bkt[PT];
    int t = threadIdx.x;
    int tile0 = blockIdx.x * PT;
    int is64 = *flag;
    sh_hist[t] = 0;
    __syncthreads();

    uint32_t rec[8]; int cb[8], rank[8];
    const uint2* e2p = (const uint2*)e;
#pragma unroll
    for (int j = 0; j < 8; ++j) {
        int idx = tile0 + j * 512 + t;
        cb[j] = -1;
        if (idx < E) {
            uint32_t s, d;
            if (is64) { s = e2p[idx].x; d = e2p[E + idx].x; }
            else      { s = e[idx];     d = e[E + idx]; }
            rec[j] = (s << CB_SHIFT) | (d & (CB_NODES - 1));
            cb[j] = (int)(d >> CB_SHIFT);
            rank[j] = atomicAdd(&sh_hist[cb[j]], 1);   // rank within (tile,bucket)
        }
    }
    __syncthreads();
    int c = sh_hist[t];
    int lane = t & 63, w = t >> 6;
    int incl = c;
    for (int o = 1; o < 64; o <<= 1) {
        int v = __shfl_up(incl, o);
        if (lane >= o) incl += v;
    }
    if (lane == 63) pw[w] = incl;
    __syncthreads();
    if (t < 8) {
        int v = pw[t];
        int inc2 = v;
#pragma unroll
        for (int o = 1; o < 8; o <<= 1) {
            int u = __shfl_up(inc2, o);
            if (t >= o) inc2 += u;
        }
        pw[t] = inc2 - v;   // exclusive
    }
    __syncthreads();
    {
        int ex = pw[w] + incl - c;
        sh_off[t] = ex;
        sh_base[t] = c ? atomicAdd(&gcur[t], c) : 0;
    }
    __syncthreads();
#pragma unroll
    for (int j = 0; j < 8; ++j) {
        if (cb[j] >= 0) {
            int slot = sh_off[cb[j]] + rank[j];
            sh_buf[slot] = rec[j];
            sh_bkt[slot] = (uint16_t)cb[j];
        }
    }
    __syncthreads();
    int total = min(PT, E - tile0);
    for (int i = t; i < total; i += 512) {
        int b = sh_bkt[i];
        int dest = sh_base[b] + (i - sh_off[b]);
        parts[(size_t)b * CAP + dest] = sh_buf[i];
    }
}

// ---- per bucket: hist -> scan -> perm4/dinv -> LDS counting-sort -> coalesced col ----
__global__ __launch_bounds__(512) void k_build(const uint32_t* __restrict__ parts,
                                               const int* __restrict__ gcur,
                                               float* __restrict__ dinv,
                                               int4* __restrict__ perm4,
                                               uint32_t* __restrict__ col, int N) {
    __shared__ int hist[CB_NODES], cur[CB_NODES], wsum4[4];
    __shared__ uint32_t sbuf[CAP];
    int t = threadIdx.x, cb = blockIdx.x;
    if (t < 256) hist[t] = 0;
    __syncthreads();
    int cnt = gcur[cb];
    const uint32_t* rp = parts + (size_t)cb * CAP;
    for (int i = t; i < cnt; i += 512) atomicAdd(&hist[rp[i] & (CB_NODES - 1)], 1);
    __syncthreads();
    int h = 0, incl = 0;
    if (t < 256) {
        h = hist[t];
        int lane = t & 63;
        incl = h;
        for (int o = 1; o < 64; o <<= 1) {
            int v = __shfl_up(incl, o);
            if (lane >= o) incl += v;
        }
        if (lane == 63) wsum4[t >> 6] = incl;
    }
    __syncthreads();
    if (t == 0) {
        int r = 0;
        for (int k = 0; k < 4; ++k) { int v = wsum4[k]; wsum4[k] = r; r += v; }
    }
    __syncthreads();
    if (t < 256) {
        int ex = wsum4[t >> 6] + incl - h;
        cur[t] = ex;
        int n = cb * CB_NODES + t;
        int base = cb * CAP;
        if (n < N) {
            float dv = rsqrtf((float)(h + 1));
            dinv[n] = dv;
            perm4[n] = make_int4(base + ex, h, n, __float_as_int(dv));
        }
    }
    __syncthreads();
    for (int i = t; i < cnt; i += 512) {
        uint32_t rec = rp[i];
        int pos = atomicAdd(&cur[rec & (CB_NODES - 1)], 1);
        sbuf[pos] = rec >> CB_SHIFT;
    }
    __syncthreads();
    int base = cb * CAP;
    for (int i = t; i < cnt; i += 512) col[base + i] = sbuf[i];   // coalesced
}

// ---- h' = bf16( dinv[n] * (A@W)[n] ), A f32 or bf16 ----
template<int ABF16>
__global__ __launch_bounds__(256) void k_gemm(const void* __restrict__ Ap,
                                              const float* __restrict__ W,
                                              const float* __restrict__ dinv,
                                              uint16_t* __restrict__ out, int N) {
    __shared__ __align__(16) float xT[64 * 68];
    __shared__ __align__(16) float Wl[64 * 64];
    int t = threadIdx.x;
#pragma unroll
    for (int j = 0; j < 16; ++j) Wl[j * 256 + t] = W[j * 256 + t];
    int n0 = blockIdx.x * 64;
    int nvalid = min(64, N - n0);
#pragma unroll
    for (int j = 0; j < 4; ++j) {
        int flat = j * 256 + t;
        int node = flat >> 4;
        int k4 = (flat & 15) * 4;
        float4 v = make_float4(0.f, 0.f, 0.f, 0.f);
        if (node < nvalid) {
            if (ABF16) {
                ushort4 u = *((const ushort4*)Ap + ((size_t)(n0 + node) * 16 + (k4 >> 2)));
                v = make_float4(bfu(u.x), bfu(u.y), bfu(u.z), bfu(u.w));
            } else {
                v = *(const float4*)((const float*)Ap + (size_t)(n0 + node) * 64 + k4);
            }
        }
        xT[(k4 + 0) * 68 + node] = v.x;
        xT[(k4 + 1) * 68 + node] = v.y;
        xT[(k4 + 2) * 68 + node] = v.z;
        xT[(k4 + 3) * 68 + node] = v.w;
    }
    __syncthreads();
    int ng = t >> 4, cg = t & 15;
    float acc[4][4] = {};
#pragma unroll 8
    for (int k = 0; k < 64; ++k) {
        float4 a = *(const float4*)&xT[k * 68 + 4 * ng];
        float4 b = *(const float4*)&Wl[k * 64 + 4 * cg];
        float av[4] = {a.x, a.y, a.z, a.w};
        float bv[4] = {b.x, b.y, b.z, b.w};
#pragma unroll
        for (int i = 0; i < 4; ++i)
#pragma unroll
            for (int j = 0; j < 4; ++j) acc[i][j] = fmaf(av[i], bv[j], acc[i][j]);
    }
#pragma unroll
    for (int i = 0; i < 4; ++i) {
        int ln = 4 * ng + i;
        if (ln < nvalid) {
            int n = n0 + ln;
            float dv = dinv[n];
            ushort4 o;
            o.x = f2bf(acc[i][0] * dv);
            o.y = f2bf(acc[i][1] * dv);
            o.z = f2bf(acc[i][2] * dv);
            o.w = f2bf(acc[i][3] * dv);
            *(ushort4*)&out[(size_t)n * 64 + 4 * cg] = o;
        }
    }
}

// ---- agg: wave = 4 nodes x 2 edge-slots x 8 feature-groups ----
// OBF16: write bf16 (layer-1 intermediate). CLS: fused classifier; hstage
// padded to 68 floats/row so the 4 slots' broadcast reads hit 4 banks.
template<int OBF16, int CLS>
__global__ __launch_bounds__(512) void k_agg(const uint16_t* __restrict__ h,
                                             const int4* __restrict__ perm4,
                                             const uint32_t* __restrict__ col,
                                             const float* __restrict__ bias,
                                             void* __restrict__ out,
                                             const float* __restrict__ Wc,
                                             const float* __restrict__ bc,
                                             float* __restrict__ outc, int N) {
    __shared__ __align__(16) float WcL[CLS ? 64 * 32 : 1];
    __shared__ __align__(16) float hstage[CLS ? 8 : 1][4][68];   // 68: bank-pad
    int t = threadIdx.x;
    if (CLS) {
#pragma unroll
        for (int j = 0; j < 4; ++j) WcL[j * 512 + t] = Wc[j * 512 + t];
        __syncthreads();
    }
    int lane = t & 63, wid = t >> 6;
    int sub  = (lane >> 3) & 1;  // edge-parity 0/1
    int g = lane & 7;            // feature group
    const uint4* hp = (const uint4*)h;  // 8 x uint4 per node row
    float bv[4];
#pragma unroll
    for (int j = 0; j < 4; ++j) bv[j] = bias[g * 8 + sub * 4 + j];
    int slot = lane >> 4;
    int idx = (blockIdx.x * 8 + wid) * 4 + slot;
    bool valid = idx < N;
    int4 pi = make_int4(0, 0, 0, 0);
    if (valid) pi = perm4[idx];
    int rs = pi.x, deg = valid ? pi.y : 0, n = pi.z;
    float di = __int_as_float(pi.w);
    int m = deg;
#pragma unroll
    for (int o = 1; o < 64; o <<= 1) m = max(m, __shfl_xor(m, o));
    int trips = (m + 1) >> 1;
    float acc[8] = {};
#pragma unroll 8
    for (int it = 0; it < trips; ++it) {
        int e = 2 * it + sub;
        if (e < deg) {
            int src = (int)col[rs + e];
            uint4 v = hp[(size_t)src * 8 + g];
            acc[0] += bflo(v.x); acc[1] += bfhi(v.x);
            acc[2] += bflo(v.y); acc[3] += bfhi(v.y);
            acc[4] += bflo(v.z); acc[5] += bfhi(v.z);
            acc[6] += bflo(v.w); acc[7] += bfhi(v.w);
        }
    }
#pragma unroll
    for (int j = 0; j < 8; ++j) acc[j] += __shfl_xor(acc[j], 8);
    if (valid) {
        float s0 = sub ? acc[4] : acc[0];
        float s1 = sub ? acc[5] : acc[1];
        float s2 = sub ? acc[6] : acc[2];
        float s3 = sub ? acc[7] : acc[3];
        uint2 v = *(const uint2*)&h[(size_t)n * 64 + g * 8 + sub * 4];
        float hn0 = bflo(v.x), hn1 = bfhi(v.x), hn2 = bflo(v.y), hn3 = bfhi(v.y);
        float r0 = tanh_fast(di * (s0 + hn0) + bv[0]);
        float r1 = tanh_fast(di * (s1 + hn1) + bv[1]);
        float r2 = tanh_fast(di * (s2 + hn2) + bv[2]);
        float r3 = tanh_fast(di * (s3 + hn3) + bv[3]);
        if (OBF16) {
            ushort4 ob;
            ob.x = f2bf(r0); ob.y = f2bf(r1); ob.z = f2bf(r2); ob.w = f2bf(r3);
            *(ushort4*)&((uint16_t*)out)[(size_t)n * 64 + g * 8 + sub * 4] = ob;
        } else {
            __align__(16) float o[4] = {r0, r1, r2, r3};
            *(float4*)&((float*)out)[(size_t)n * 64 + g * 8 + sub * 4] = *(float4*)&o[0];
        }
        if (CLS)
            *(float4*)&hstage[wid][slot][g * 8 + sub * 4] = make_float4(r0, r1, r2, r3);
    }
    if (CLS) {
        // same-wave LDS exchange: all 16 lanes of this slot wrote above.
        int q = lane & 15;                 // 2 cols per lane: 2q, 2q+1
        if (valid) {
            float a0 = 0.f, a1 = 0.f;
#pragma unroll
            for (int k = 0; k < 64; k += 4) {
                float4 hv = *(const float4*)&hstage[wid][slot][k];
                float2 w0 = *(const float2*)&WcL[(k + 0) * 32 + 2 * q];
                float2 w1 = *(const float2*)&WcL[(k + 1) * 32 + 2 * q];
                float2 w2 = *(const float2*)&WcL[(k + 2) * 32 + 2 * q];
                float2 w3 = *(const float2*)&WcL[(k + 3) * 32 + 2 * q];
                a0 = fmaf(hv.x, w0.x, a0); a1 = fmaf(hv.x, w0.y, a1);
                a0 = fmaf(hv.y, w1.x, a0); a1 = fmaf(hv.y, w1.y, a1);
                a0 = fmaf(hv.z, w2.x, a0); a1 = fmaf(hv.z, w2.y, a1);
                a0 = fmaf(hv.w, w3.x, a0); a1 = fmaf(hv.w, w3.y, a1);
            }
            float2 bcv = *(const float2*)&bc[2 * q];
            float2 o = make_float2(a0 + bcv.x, a1 + bcv.y);
            *(float2*)&outc[(size_t)n * 32 + 2 * q] = o;
        }
    }
}

extern "C" void kernel_launch(void* const* d_in, const int* in_sizes, int n_in,
                              void* d_out, int out_size, void* d_ws, size_t ws_size,
                              hipStream_t stream) {
    const float*    x     = (const float*)d_in[0];
    const uint32_t* edges = (const uint32_t*)d_in[1];
    const float*    W1    = (const float*)d_in[2];
    const float*    b1    = (const float*)d_in[3];
    const float*    W2    = (const float*)d_in[4];
    const float*    b2    = (const float*)d_in[5];
    const float*    Wc    = (const float*)d_in[6];
    const float*    bc    = (const float*)d_in[7];

    const int N   = in_sizes[0] / 64;
    const int E   = in_sizes[1] / 2;
    const int NBC = (N + CB_NODES - 1) >> CB_SHIFT;          // 391
    const int NTG = (N + 63) / 64;                           // 1563
    const int NTP = (E + PT - 1) / PT;                       // 293
    const int NAG = (N + 31) / 32;                           // 8 waves x 4 nodes per block

    char* w = (char*)d_ws;
    size_t off = 0;
    auto alloc = [&](size_t bytes) {
        void* p = w + off;
        off = (off + bytes + 255) & ~(size_t)255;
        return p;
    };
    int*      flag   = (int*)alloc(4);
    int*      gcur   = (int*)alloc(NBINS * 4);
    float*    dinv   = (float*)alloc((size_t)N * 4);
    uint32_t* parts  = (uint32_t*)alloc((size_t)NBC * CAP * 4);
    uint32_t* col    = (uint32_t*)alloc((size_t)NBC * CAP * 4);
    int4*     perm4  = (int4*)alloc((size_t)N * 16);
    uint16_t* bufA   = (uint16_t*)alloc((size_t)N * 64 * 2);
    uint16_t* bufB   = (uint16_t*)alloc((size_t)N * 64 * 2);

    float* outc = (float*)d_out;            // chunk0: N x 32
    float* hfin = outc + (size_t)N * 32;    // chunk1: N x 64

    hipLaunchKernelGGL(k_init, dim3(1), dim3(256), 0, stream, edges, E, flag, gcur);
    hipLaunchKernelGGL(k_part, dim3(NTP), dim3(512), 0, stream, edges, E, flag, gcur, parts);
    hipLaunchKernelGGL(k_build, dim3(NBC), dim3(512), 0, stream, parts, gcur, dinv, perm4, col, N);

    // layer 1: h1' = bf16(dinv*(x@W1)) -> bufA ; h2 = bf16(tanh(agg(h1')+b1)) -> bufB
    hipLaunchKernelGGL(HIP_KERNEL_NAME(k_gemm<0>), dim3(NTG), dim3(256), 0, stream,
                       (const void*)x, W1, dinv, bufA, N);
    hipLaunchKernelGGL(HIP_KERNEL_NAME(k_agg<1, 0>), dim3(NAG), dim3(512), 0, stream,
                       bufA, perm4, col, b1, (void*)bufB, (const float*)nullptr,
                       (const float*)nullptr, (float*)nullptr, N);
    // layer 2: g' = bf16(dinv*(h2@W2)) -> bufA ; h = tanh(agg(g')+b2) -> hfin (f32)
    //          + fused classifier: outc = h @ Wc + bc
    hipLaunchKernelGGL(HIP_KERNEL_NAME(k_gemm<1>), dim3(NTG), dim3(256), 0, stream,
                       (const void*)bufB, W2, dinv, bufA, N);
    hipLaunchKernelGGL(HIP_KERNEL_NAME(k_agg<0, 1>), dim3(NAG), dim3(512), 0, stream,
                       bufA, perm4, col, b2, (void*)hfin, Wc, bc, outc, N);
}